// Round 8
// baseline (8256.281 us; speedup 1.0000x reference)
//
#include <hip/hip_runtime.h>
#include <math.h>

#define NB 16
#define NT 512
#define NE 1024
#define ND 1024
#define NA 1024
#define NO 10000
#define NL 128
#define NOL 129
#define NROWS (NB*NOL)   /* 2064 */
#define TOK_SOS 9999
#define TOK_EOS 9999
#define NBLK 256
#define NGW 64           /* gate-GEMM workgroups */

typedef unsigned short u16;
typedef unsigned int u32;
typedef __bf16 bf16x8 __attribute__((ext_vector_type(8)));
typedef float f32x4 __attribute__((ext_vector_type(4)));
typedef unsigned short u16x8 __attribute__((ext_vector_type(8)));
typedef unsigned short u16x4 __attribute__((ext_vector_type(4)));

__device__ __forceinline__ float sigf(float x){ return 1.0f/(1.0f+expf(-x)); }
__device__ __forceinline__ float b2f(u16 s){
  union { u32 i; float f; } u; u.i = ((u32)s) << 16; return u.f;
}
__device__ __forceinline__ u16 f2b(float f){
  union { float f; u32 i; } u; u.f = f;
  u32 r = u.i + 0x7FFFu + ((u.i >> 16) & 1u);
  return (u16)(r >> 16);
}
__device__ __forceinline__ bf16x8 cvt8(float4 a, float4 b){
  union { u16 u[8]; bf16x8 v; } c;
  c.u[0]=f2b(a.x); c.u[1]=f2b(a.y); c.u[2]=f2b(a.z); c.u[3]=f2b(a.w);
  c.u[4]=f2b(b.x); c.u[5]=f2b(b.y); c.u[6]=f2b(b.z); c.u[7]=f2b(b.w);
  return c.v;
}
__device__ __forceinline__ bf16x8 zero8(){
  union { u16 u[8]; bf16x8 v; } c;
  #pragma unroll
  for (int i=0;i<8;++i) c.u[i]=0;
  return c.v;
}

// ---- coherent producer stores / flag ops (agent scope = sc0, L3-served) ----
__device__ __forceinline__ void coh_stf(float* p, float v){
  __hip_atomic_store(p, v, __ATOMIC_RELAXED, __HIP_MEMORY_SCOPE_AGENT);
}
__device__ __forceinline__ u32 coh_ldu(const u32* p){
  return __hip_atomic_load((u32*)p, __ATOMIC_RELAXED, __HIP_MEMORY_SCOPE_AGENT);
}
__device__ __forceinline__ void coh_stu(u32* p, u32 v){
  __hip_atomic_store(p, v, __ATOMIC_RELAXED, __HIP_MEMORY_SCOPE_AGENT);
}

// ---- wide agent-coherent loads (sc0 only: bypass L1/L2, HIT Infinity Cache) ----
__device__ __forceinline__ uint4 sc_ld128(const void* p){
  uint4 r;
  asm volatile("global_load_dwordx4 %0, %1, off sc0" : "=v"(r) : "v"(p));
  return r;
}
__device__ __forceinline__ uint2 sc_ld64(const void* p){
  uint2 r;
  asm volatile("global_load_dwordx2 %0, %1, off sc0" : "=v"(r) : "v"(p));
  return r;
}
__device__ __forceinline__ void sc_wait(){
  asm volatile("s_waitcnt vmcnt(0)" ::: "memory");
  __builtin_amdgcn_sched_barrier(0);
}

// stage 32KB global->LDS, conflict-free (lane-consecutive 16B)
__device__ __forceinline__ void stage32(const char* g, char* l, int tid){
  uint4 v[8];
  #pragma unroll
  for (int i=0;i<8;++i) v[i] = sc_ld128(g + i*4096 + tid*16);
  sc_wait();
  #pragma unroll
  for (int i=0;i<8;++i) *(uint4*)(l + i*4096 + tid*16) = v[i];
}

// z/attc swizzle: u16-unit offset of element (b, d) in a [16][1024] buffer
__device__ __forceinline__ int zswz(int b, int d){
  return b*1024 + ((((d)>>3) ^ (b&7)) << 3) + (d&7);
}
// LDS fragment read (un-swizzled): 8 u16 = elems [blk*8 .. blk*8+7] of row
__device__ __forceinline__ bf16x8 lds_frag(const u16* s, int row, int blk){
  return *(const bf16x8*)(s + row*1024 + ((blk ^ (row&7)) << 3));
}

// ---- dataflow flag protocol ----
// producer: all threads drain payload stores, then tid0 publishes epoch
__device__ __forceinline__ void flag_set(u32* f, int ep){
  asm volatile("s_waitcnt vmcnt(0)" ::: "memory");
  __syncthreads();
  if (threadIdx.x == 0) coh_stu(f, (u32)ep);
}
// consumer: threads 0..n-1 poll one flag each, then join
__device__ __forceinline__ void flag_wait(const u32* f, int n, int ep){
  if ((int)threadIdx.x < n){
    while ((int)coh_ldu(f + threadIdx.x) < ep) __builtin_amdgcn_s_sleep(2);
  }
  __syncthreads();
}

// ---------------- zero ----------------
__global__ void zero4_kernel(uint4* __restrict__ p, int n){
  int i = blockIdx.x*256 + threadIdx.x;
  if (i < n) p[i] = make_uint4(0,0,0,0);
}

// ---------------- f32 [4096][ld] (col slice) -> bf16 [4096][1024] ----------------
__global__ __launch_bounds__(256) void cvt_nk_kernel(
    const float* __restrict__ src, int ld, int off, u16* __restrict__ dst){
  int i = (blockIdx.x*256 + threadIdx.x)*4;
  int row = i >> 10, col = i & 1023;
  float4 v = *(const float4*)(src + (size_t)row*ld + off + col);
  u16x4 o = { f2b(v.x), f2b(v.y), f2b(v.z), f2b(v.w) };
  *(u16x4*)(dst + i) = o;
}

// ---------------- transpose-convert: src f32 [R][C] -> dst bf16 [C'][R] ----------------
__global__ __launch_bounds__(256) void tcvt_kernel(
    const float* __restrict__ src, int R, int C, u16* __restrict__ dst){
  __shared__ float tile[32][33];
  const int c0 = blockIdx.x*32, r0 = blockIdx.y*32;
  const int tx = threadIdx.x & 31, ty = threadIdx.x >> 5;
  #pragma unroll
  for (int k = 0; k < 4; ++k){
    int rr = ty + k*8;
    int c = c0 + tx;
    float v = (c < C) ? src[(size_t)(r0+rr)*C + c] : 0.0f;
    tile[rr][tx] = v;
  }
  __syncthreads();
  #pragma unroll
  for (int k = 0; k < 4; ++k){
    int cc = ty + k*8;
    dst[(size_t)(c0+cc)*R + r0 + tx] = f2b(tile[tx][cc]);
  }
}

// ---------------- hpad [16][512][1024] f32 -> masked bf16 transposed [16][1024][512] -------
__global__ __launch_bounds__(256) void hpadT_kernel(
    const float* __restrict__ hpad, const int* __restrict__ hlen, u16* __restrict__ dst){
  __shared__ float tile[32][33];
  const int e0 = blockIdx.x*32, t0 = blockIdx.y*32, b = blockIdx.z;
  const int tx = threadIdx.x & 31, ty = threadIdx.x >> 5;
  const int len = hlen[b];
  #pragma unroll
  for (int k = 0; k < 4; ++k){
    int r = ty + k*8;
    tile[r][tx] = hpad[((size_t)b*512 + t0 + r)*1024 + e0 + tx];
  }
  __syncthreads();
  #pragma unroll
  for (int k = 0; k < 4; ++k){
    int el = ty + k*8;
    float m = (t0 + tx < len) ? 1.0f : 0.0f;
    dst[((size_t)b*1024 + e0 + el)*512 + t0 + tx] = f2b(tile[tx][el]*m);
  }
}

// ---------------- bias1 = bih1 + bhh1 ----------------
__global__ void bias_add_kernel(const float* __restrict__ a, const float* __restrict__ b,
                                float* __restrict__ o){
  int i = blockIdx.x*256 + threadIdx.x;
  if (i < 4096) o[i] = a[i] + b[i];
}

// ---------------- pre_enc = tanh(mask(hpad) @ Wenc) via MFMA -> bf16 [8192][1024] ----------
__global__ __launch_bounds__(256) void preenc_mfma(
    const float* __restrict__ hpad, const int* __restrict__ hlen,
    const u16* __restrict__ wencT, u16* __restrict__ pre){
  const int m0 = blockIdx.x*64, n0 = blockIdx.y*64;
  const int tid = threadIdx.x, lane = tid & 63, wv = tid >> 6;
  const int r = lane & 15, q = lane >> 4;
  const int ar = m0 + wv*16 + r;
  const bool on = (ar & 511) < hlen[ar >> 9];
  const float* ap = hpad + (size_t)ar*1024 + q*8;
  f32x4 acc[4] = {{0,0,0,0},{0,0,0,0},{0,0,0,0},{0,0,0,0}};
  for (int kt = 0; kt < 32; ++kt){
    bf16x8 a;
    if (on){
      float4 v0 = *(const float4*)(ap + kt*32);
      float4 v1 = *(const float4*)(ap + kt*32 + 4);
      a = cvt8(v0, v1);
    } else a = zero8();
    #pragma unroll
    for (int s = 0; s < 4; ++s){
      const u16* bp = wencT + (size_t)(n0 + s*16 + r)*1024 + kt*32 + q*8;
      acc[s] = __builtin_amdgcn_mfma_f32_16x16x32_bf16(a, *(const bf16x8*)bp, acc[s], 0,0,0);
    }
  }
  #pragma unroll
  for (int s = 0; s < 4; ++s)
    #pragma unroll
    for (int rr = 0; rr < 4; ++rr){
      int row = m0 + wv*16 + q*4 + rr, col = n0 + s*16 + r;
      pre[(size_t)row*1024 + col] = f2b(tanhf(acc[s][rr]));
    }
}

// ---------------- gey = embed[ys_in] @ Wih0[:,0:1024]^T + bih0 + bhh0 via MFMA -> bf16 -----
__global__ __launch_bounds__(256) void gey_mfma(
    const int* __restrict__ ys, const float* __restrict__ embed,
    const float* __restrict__ Wih0, const float* __restrict__ bih0,
    const float* __restrict__ bhh0, u16* __restrict__ gey){
  const int m0 = blockIdx.x*64, n0 = blockIdx.y*64;
  const int tid = threadIdx.x, lane = tid & 63, wv = tid >> 6;
  const int r = lane & 15, q = lane >> 4;
  const int ar = m0 + wv*16 + r;
  int tok = 0;
  if (ar < NROWS){
    int bb = ar / NOL, l = ar - bb*NOL;
    tok = (l==0) ? TOK_SOS : ys[bb*NL + l - 1];
  }
  const float* ap = embed + (size_t)tok*1024 + q*8;
  f32x4 acc[4] = {{0,0,0,0},{0,0,0,0},{0,0,0,0},{0,0,0,0}};
  for (int kt = 0; kt < 32; ++kt){
    float4 v0 = *(const float4*)(ap + kt*32);
    float4 v1 = *(const float4*)(ap + kt*32 + 4);
    bf16x8 a = cvt8(v0, v1);
    #pragma unroll
    for (int s = 0; s < 4; ++s){
      const float* bp = Wih0 + (size_t)(n0 + s*16 + r)*2048 + kt*32 + q*8;
      float4 w0 = *(const float4*)(bp);
      float4 w1 = *(const float4*)(bp + 4);
      acc[s] = __builtin_amdgcn_mfma_f32_16x16x32_bf16(a, cvt8(w0,w1), acc[s], 0,0,0);
    }
  }
  #pragma unroll
  for (int s = 0; s < 4; ++s)
    #pragma unroll
    for (int rr = 0; rr < 4; ++rr){
      int row = m0 + wv*16 + q*4 + rr, col = n0 + s*16 + r;
      if (row < NROWS)
        gey[(size_t)row*4096 + col] = f2b(acc[s][rr] + bih0[col] + bhh0[col]);
    }
}

// ---------------- logits = zallb @ woutT^T + bout via MFMA -> bf16 [2064][10000] -----------
__global__ __launch_bounds__(256) void logits_mfma(
    const u16* __restrict__ zallb, const u16* __restrict__ woutT,
    const float* __restrict__ bout, u16* __restrict__ logits){
  const int m0 = blockIdx.x*64, n0 = blockIdx.y*64;
  const int tid = threadIdx.x, lane = tid & 63, wv = tid >> 6;
  const int r = lane & 15, q = lane >> 4;
  const int ar = m0 + wv*16 + r;
  const u16* ap = zallb + (size_t)ar*1024 + q*8;
  f32x4 acc[4] = {{0,0,0,0},{0,0,0,0},{0,0,0,0},{0,0,0,0}};
  for (int kt = 0; kt < 32; ++kt){
    bf16x8 a = *(const bf16x8*)(ap + kt*32);
    #pragma unroll
    for (int s = 0; s < 4; ++s){
      const u16* bp = woutT + (size_t)(n0 + s*16 + r)*1024 + kt*32 + q*8;
      acc[s] = __builtin_amdgcn_mfma_f32_16x16x32_bf16(a, *(const bf16x8*)bp, acc[s], 0,0,0);
    }
  }
  #pragma unroll
  for (int s = 0; s < 4; ++s)
    #pragma unroll
    for (int rr = 0; rr < 4; ++rr){
      int row = m0 + wv*16 + q*4 + rr, col = n0 + s*16 + r;
      if (row < NROWS && col < NO)
        logits[(size_t)row*NO + col] = f2b(acc[s][rr] + bout[col]);
    }
}

// ---------------- persistent sequential kernel: barrier-free dataflow ----------------
// 256 WGs; WGs 0..63 are gate-WGs (wave = gate, WG owns d = wg*16..+15).
// Flags: fA[64] (dq+z1 ready), fB[256] (esc rows), fC[256] (attc slices), fD[64] (z0).
__global__ __launch_bounds__(256, 1) void seq_kernel(
    const u16* __restrict__ pre,    // [8192][1024] bf16 (cached)
    const u16* __restrict__ hpadT,  // [16][1024][512] bf16 masked (cached)
    const u16* __restrict__ w0c,    // [4096][1024] Wih0[:,1024:] bf16 (cached)
    const u16* __restrict__ wh0,    // [4096][1024] (cached)
    const u16* __restrict__ w1c,    // [4096][1024] (cached)
    const u16* __restrict__ wh1,    // [4096][1024] (cached)
    const u16* __restrict__ wdecT,  // [1024 n][1024 k] bf16 (cached)
    const u16* __restrict__ gey,    // [2064][4096] bf16 (cached)
    const float* __restrict__ bias1,// [4096] (cached)
    const int* __restrict__ hlen,
    float* dqf,                     // [16][1024] f32 (coherent)
    float* esc,                     // [16][512] f32 (coherent)
    u16* attc,                      // [16][1024] bf16 swizzled (coherent)
    u16* z0bf, u16* z1bf,           // [2][16][1024] bf16 swizzled ping-pong (coherent)
    u16* zallb,                     // [2112][1024] bf16 (normal stores)
    u32* af)
{
  const int wg = blockIdx.x, tid = threadIdx.x;
  const int lane = tid & 63, wv = tid >> 6;
  const int r = lane & 15, q = lane >> 4;
  u32* fA = af;          // 64
  u32* fB = af + 64;     // 256
  u32* fC = af + 320;    // 256
  u32* fD = af + 576;    // 64

  extern __shared__ __align__(16) char dynlds[];
  u16*   sZ0  = (u16*)dynlds;              // 32KB
  u16*   sZ1  = (u16*)(dynlds + 32768);    // 32KB (aliased as sAt in phase D)
  float* sDq  = (float*)(dynlds + 65536);  // 4KB
  float* sEsc = (float*)(dynlds + 69632);  // 2KB
  u16*   sAt  = sZ1;
  __shared__ float gex[4][16][16];
  __shared__ float sred[256];
  __shared__ float sw[512];
  __shared__ float spart[4][64];

  float c0r = 0.f, c1r = 0.f;   // cell state for (b=tid>>4, d=wg*16+(tid&15)) in gate-WGs

  for (int t = 0; t <= NOL; ++t){
    const int cur = t & 1, prv = cur ^ 1;

    // ======== Phase A (gate-WGs): gemm1+cell1(t-1), dq(t) ========
    if (wg < NGW){
      // wait: z0(t-1) [fD >= t] and z1(t-2)+prior dq epoch [fA >= t]
      if (tid < 64){
        while ((int)coh_ldu(fA + tid) < t) __builtin_amdgcn_s_sleep(2);
      } else if (tid < 128){
        while ((int)coh_ldu(fD + tid - 64) < t) __builtin_amdgcn_s_sleep(2);
      }
      __syncthreads();
      stage32((const char*)(z0bf + prv*16384), (char*)sZ0, tid);
      stage32((const char*)(z1bf + cur*16384), (char*)sZ1, tid);
      __syncthreads();
      if (t >= 1){
        const int s = t - 1;
        f32x4 acc = {0.f,0.f,0.f,0.f};
        const u16* B1 = w1c + (size_t)(wv*1024 + wg*16 + r)*1024 + q*8;
        const u16* B2 = wh1 + (size_t)(wv*1024 + wg*16 + r)*1024 + q*8;
        #pragma unroll 8
        for (int kt = 0; kt < 32; ++kt)
          acc = __builtin_amdgcn_mfma_f32_16x16x32_bf16(
                  lds_frag(sZ0, r, kt*4+q), *(const bf16x8*)(B1 + kt*32), acc, 0,0,0);
        #pragma unroll 8
        for (int kt = 0; kt < 32; ++kt)
          acc = __builtin_amdgcn_mfma_f32_16x16x32_bf16(
                  lds_frag(sZ1, r, kt*4+q), *(const bf16x8*)(B2 + kt*32), acc, 0,0,0);
        #pragma unroll
        for (int rr = 0; rr < 4; ++rr) gex[wv][q*4+rr][r] = acc[rr];
        __syncthreads();
        {
          int b = tid >> 4, dd = tid & 15, d = wg*16 + dd;
          float g0 = gex[0][b][dd] + bias1[d];
          float g1 = gex[1][b][dd] + bias1[1024 + d];
          float g2 = gex[2][b][dd] + bias1[2048 + d];
          float g3 = gex[3][b][dd] + bias1[3072 + d];
          float cn = sigf(g1)*c1r + sigf(g0)*tanhf(g2);
          float zn = sigf(g3)*tanhf(cn);
          c1r = cn;
          float zn2 = __shfl_down(zn, 1);
          if ((tid & 1) == 0){
            u32 pk = (u32)f2b(zn) | ((u32)f2b(zn2) << 16);
            *(u32*)(zallb + ((size_t)b*NOL + s)*1024 + d) = pk;       // normal store
            coh_stu((u32*)(z1bf + prv*16384 + zswz(b, d)), pk);
          }
        }
        __syncthreads();   // gex reuse below
      }
      if (t < NOL){
        f32x4 acc = {0.f,0.f,0.f,0.f};
        const u16* Bd = wdecT + (size_t)(wg*16 + r)*1024 + q*8;
        #pragma unroll
        for (int i = 0; i < 8; ++i){
          int kt = wv*8 + i;
          acc = __builtin_amdgcn_mfma_f32_16x16x32_bf16(
                  lds_frag(sZ0, r, kt*4+q), *(const bf16x8*)(Bd + kt*32), acc, 0,0,0);
        }
        #pragma unroll
        for (int rr = 0; rr < 4; ++rr) gex[wv][q*4+rr][r] = acc[rr];
        __syncthreads();
        {
          int b = tid >> 4, j = tid & 15;
          float s2 = gex[0][b][j] + gex[1][b][j] + gex[2][b][j] + gex[3][b][j];
          coh_stf(&dqf[b*1024 + wg*16 + j], tanhf(s2));
        }
        flag_set(fA + wg, t + 1);
      }
    }
    if (t == NOL) break;

    // ======== Phase B: escore = 2 * pre . dq  (all 256 WGs, 32 rows each) ========
    {
      const int b = wg >> 4;
      flag_wait(fA, 64, t + 1);
      { uint4 v = sc_ld128((const char*)(dqf + b*1024) + tid*16);
        sc_wait();
        *(uint4*)((char*)sDq + tid*16) = v; }
      __syncthreads();
      const int rbase = wg*32 + wv*8;
      float qv[16];
      #pragma unroll
      for (int i = 0; i < 4; ++i)
        *(float4*)(qv + i*4) = *(const float4*)(sDq + lane*16 + i*4);
      #pragma unroll
      for (int rr = 0; rr < 8; ++rr){
        const u16* pr = pre + (size_t)(rbase+rr)*1024 + lane*16;
        u16x8 p0 = *(const u16x8*)(pr);
        u16x8 p1 = *(const u16x8*)(pr+8);
        float acc = 0.f;
        #pragma unroll
        for (int j = 0; j < 8; ++j){
          acc += b2f(p0[j])*qv[j];
          acc += b2f(p1[j])*qv[8+j];
        }
        #pragma unroll
        for (int off = 32; off > 0; off >>= 1) acc += __shfl_xor(acc, off, 64);
        if (lane == 0) coh_stf(&esc[rbase+rr], 2.0f*acc);
      }
      flag_set(fB + wg, t + 1);
    }

    // ======== Phase C: softmax + att_c (b = wg>>4, 64-col e-slice) ========
    {
      const int b = wg >> 4, ec = wg & 15;
      flag_wait(fB + b*16, 16, t + 1);
      { uint2 v = sc_ld64((const char*)(esc + b*512) + tid*8);
        sc_wait();
        *(uint2*)((char*)sEsc + tid*8) = v; }
      __syncthreads();
      const int len = hlen[b];
      float e0 = (tid < len)     ? sEsc[tid]       : -INFINITY;
      float e1 = (tid+256 < len) ? sEsc[tid + 256] : -INFINITY;
      sred[tid] = fmaxf(e0, e1);
      __syncthreads();
      #pragma unroll
      for (int s2 = 128; s2 > 0; s2 >>= 1){
        if (tid < s2) sred[tid] = fmaxf(sred[tid], sred[tid+s2]);
        __syncthreads();
      }
      float mx = sred[0];
      __syncthreads();
      float p0 = (tid < len)     ? expf(e0 - mx) : 0.0f;
      float p1 = (tid+256 < len) ? expf(e1 - mx) : 0.0f;
      sred[tid] = p0 + p1;
      __syncthreads();
      #pragma unroll
      for (int s2 = 128; s2 > 0; s2 >>= 1){
        if (tid < s2) sred[tid] += sred[tid+s2];
        __syncthreads();
      }
      float inv = 1.0f/sred[0];
      sw[tid] = p0*inv; sw[tid+256] = p1*inv;
      __syncthreads();
      const int el = tid & 63, th = tid >> 6;
      const u16* hp = hpadT + ((size_t)b*1024 + ec*64 + el)*512 + th*128;
      float acc = 0.f;
      #pragma unroll
      for (int i = 0; i < 16; ++i){
        u16x8 v = *(const u16x8*)(hp + i*8);
        #pragma unroll
        for (int j = 0; j < 8; ++j) acc += sw[th*128 + i*8 + j]*b2f(v[j]);
      }
      spart[th][el] = acc;
      __syncthreads();
      if (tid < 64){
        float s2 = spart[0][tid]+spart[1][tid]+spart[2][tid]+spart[3][tid];
        float s2n = __shfl_down(s2, 1);
        if ((tid & 1) == 0){
          int e = ec*64 + tid;
          u32 pk = (u32)f2b(s2) | ((u32)f2b(s2n) << 16);
          coh_stu((u32*)(attc + zswz(b, e)), pk);
        }
      }
      flag_set(fC + wg, t + 1);
    }

    // ======== Phase D (gate-WGs): gemm0 + cell0(t) -> z0(t) ========
    if (wg < NGW){
      flag_wait(fC, 256, t + 1);
      stage32((const char*)attc, (char*)sAt, tid);
      __syncthreads();
      f32x4 acc = {0.f,0.f,0.f,0.f};
      const u16* B1 = w0c + (size_t)(wv*1024 + wg*16 + r)*1024 + q*8;
      const u16* B2 = wh0 + (size_t)(wv*1024 + wg*16 + r)*1024 + q*8;
      #pragma unroll 8
      for (int kt = 0; kt < 32; ++kt)
        acc = __builtin_amdgcn_mfma_f32_16x16x32_bf16(
                lds_frag(sAt, r, kt*4+q), *(const bf16x8*)(B1 + kt*32), acc, 0,0,0);
      #pragma unroll 8
      for (int kt = 0; kt < 32; ++kt)
        acc = __builtin_amdgcn_mfma_f32_16x16x32_bf16(
                lds_frag(sZ0, r, kt*4+q), *(const bf16x8*)(B2 + kt*32), acc, 0,0,0);
      #pragma unroll
      for (int rr = 0; rr < 4; ++rr) gex[wv][q*4+rr][r] = acc[rr];
      __syncthreads();
      {
        int b = tid >> 4, dd = tid & 15, d = wg*16 + dd;
        const u16* gr = gey + ((size_t)b*NOL + t)*4096 + d;
        float g0 = gex[0][b][dd] + b2f(gr[0]);
        float g1 = gex[1][b][dd] + b2f(gr[1024]);
        float g2 = gex[2][b][dd] + b2f(gr[2048]);
        float g3 = gex[3][b][dd] + b2f(gr[3072]);
        float cn = sigf(g1)*c0r + sigf(g0)*tanhf(g2);
        float zn = sigf(g3)*tanhf(cn);
        c0r = cn;
        float zn2 = __shfl_down(zn, 1);
        if ((tid & 1) == 0){
          u32 pk = (u32)f2b(zn) | ((u32)f2b(zn2) << 16);
          coh_stu((u32*)(z0bf + cur*16384 + zswz(b, d)), pk);
        }
      }
      flag_set(fD + wg, t + 1);
    }
  }
}

// ---------------- per-row log_softmax + NLL + argmax (bf16 logits) ----------------
__global__ __launch_bounds__(256) void loss_kernel(
    const u16* __restrict__ logits, const int* __restrict__ ys, float* __restrict__ accum){
  int row = blockIdx.x;
  int tid = threadIdx.x;
  const u16* lr = logits + (size_t)row * NO;
  __shared__ float sv[256];
  __shared__ int   si[256];
  float mx = -INFINITY; int mi = 0;
  for (int n = tid; n < NO; n += 256){
    float v = b2f(lr[n]);
    if (v > mx){ mx = v; mi = n; }
  }
  sv[tid] = mx; si[tid] = mi;
  __syncthreads();
  for (int s=128; s>0; s>>=1){
    if (tid < s){
      if (sv[tid+s] > sv[tid] || (sv[tid+s]==sv[tid] && si[tid+s] < si[tid])){
        sv[tid] = sv[tid+s]; si[tid] = si[tid+s];
      }
    }
    __syncthreads();
  }
  float gmx = sv[0]; int gmi = si[0];
  __syncthreads();
  float ps = 0.0f;
  for (int n = tid; n < NO; n += 256) ps += expf(b2f(lr[n])-gmx);
  sv[tid] = ps;
  __syncthreads();
  for (int s=128; s>0; s>>=1){ if (tid<s) sv[tid] += sv[tid+s]; __syncthreads(); }
  if (tid==0){
    int b = row / NOL, l = row - b*NOL;
    int label = (l < NL) ? ys[b*NL + l] : TOK_EOS;
    float lse = gmx + logf(sv[0]);
    float nll = lse - b2f(lr[label]);
    atomicAdd(&accum[0], nll);
    atomicAdd(&accum[1], (gmi==label) ? 1.0f : 0.0f);
  }
}

__global__ void finalize_kernel(const float* __restrict__ accum, float* __restrict__ out){
  out[0] = accum[0] / (float)NROWS * (float)(NOL-1);
  out[1] = accum[1] / (float)NROWS;
}

extern "C" void kernel_launch(void* const* d_in, const int* in_sizes, int n_in,
                              void* d_out, int out_size, void* d_ws, size_t ws_size,
                              hipStream_t stream){
  const float* hpad  = (const float*)d_in[0];
  const int*   hlen  = (const int*)  d_in[1];
  const int*   ys    = (const int*)  d_in[2];
  const float* embed = (const float*)d_in[3];
  const float* Wenc  = (const float*)d_in[4];
  const float* Wdec  = (const float*)d_in[5];
  const float* Wih0  = (const float*)d_in[6];
  const float* Whh0  = (const float*)d_in[7];
  const float* bih0  = (const float*)d_in[8];
  const float* bhh0  = (const float*)d_in[9];
  const float* Wih1  = (const float*)d_in[10];
  const float* Whh1  = (const float*)d_in[11];
  const float* bih1  = (const float*)d_in[12];
  const float* bhh1  = (const float*)d_in[13];
  const float* Wout  = (const float*)d_in[14];
  const float* bout  = (const float*)d_in[15];
  float* out = (float*)d_out;

  char* ws = (char*)d_ws;
  size_t cur = 0;
  auto alloc = [&](size_t bytes) -> char* {
    char* p = ws + cur;
    cur += (bytes + 255) & ~(size_t)255;
    return p;
  };
  u16*   pre_bf   = (u16*)  alloc(16777216);   // [8192][1024]
  u16*   hpadT    = (u16*)  alloc(16777216);   // [16][1024][512]
  u16*   w0c      = (u16*)  alloc(8388608);    // Wih0[:,1024:]
  u16*   wh0      = (u16*)  alloc(8388608);
  u16*   w1c      = (u16*)  alloc(8388608);
  u16*   wh1      = (u16*)  alloc(8388608);
  u16*   wdecT    = (u16*)  alloc(2097152);    // [1024][1024]
  u16*   wencT    = (u16*)  alloc(2097152);    // [1024][1024]
  u16*   woutT    = (u16*)  alloc(20578304);   // [10048][1024]
  u16*   gey      = (u16*)  alloc(16908288);   // [2064][4096]
  u16*   zallb    = (u16*)  alloc(4325376);    // [2112][1024]
  u16*   logits   = (u16*)  alloc(41280000);   // [2064][10000]
  float* dqf      = (float*)alloc(65536);
  float* esc      = (float*)alloc(32768);
  u16*   attc     = (u16*)  alloc(32768);
  float* bias1    = (float*)alloc(16384);
  // ---- zeroed region (contiguous) ----
  u32*   af       = (u32*)  alloc(2560);       // flags: fA[64] fB[256] fC[256] fD[64]
  u16*   z0bf     = (u16*)  alloc(65536);      // [2][16][1024]
  u16*   z1bf     = (u16*)  alloc(65536);
  float* accum    = (float*)alloc(128);
  // zero bytes = 2560 + 65536 + 65536 + 128 = 133760 -> 8360 uint4
  zero4_kernel<<<33, 256, 0, stream>>>((uint4*)af, 8360);

  tcvt_kernel<<<dim3(32,32),  256, 0, stream>>>(Wenc, 1024, 1024, wencT);
  tcvt_kernel<<<dim3(32,32),  256, 0, stream>>>(Wdec, 1024, 1024, wdecT);
  tcvt_kernel<<<dim3(313,32), 256, 0, stream>>>(Wout, 1024, NO,   woutT);
  cvt_nk_kernel<<<4096, 256, 0, stream>>>(Wih0, 2048, 1024, w0c);
  cvt_nk_kernel<<<4096, 256, 0, stream>>>(Whh0, 1024, 0, wh0);
  cvt_nk_kernel<<<4096, 256, 0, stream>>>(Wih1, 1024, 0, w1c);
  cvt_nk_kernel<<<4096, 256, 0, stream>>>(Whh1, 1024, 0, wh1);
  hpadT_kernel<<<dim3(32,16,16), 256, 0, stream>>>(hpad, hlen, hpadT);
  bias_add_kernel<<<16, 256, 0, stream>>>(bih1, bhh1, bias1);
  preenc_mfma<<<dim3(128,16), 256, 0, stream>>>(hpad, hlen, wencT, pre_bf);
  gey_mfma<<<dim3(33,64), 256, 0, stream>>>(ys, embed, Wih0, bih0, bhh0, gey);

  hipFuncSetAttribute((const void*)seq_kernel,
                      hipFuncAttributeMaxDynamicSharedMemorySize, 71680);
  seq_kernel<<<NBLK, 256, 71680, stream>>>(pre_bf, hpadT, w0c, wh0, w1c, wh1,
                                           wdecT, gey, bias1, hlen, dqf, esc, attc,
                                           z0bf, z1bf, zallb, af);

  logits_mfma<<<dim3(33,157), 256, 0, stream>>>(zallb, woutT, bout, logits);
  loss_kernel<<<NROWS, 256, 0, stream>>>(logits, ys, accum);
  finalize_kernel<<<1, 1, 0, stream>>>(accum, out);
}

// Round 9
// 6736.539 us; speedup vs baseline: 1.2256x; 1.2256x over previous
//
#include <hip/hip_runtime.h>
#include <math.h>

#define NB 16
#define NT 512
#define NE 1024
#define ND 1024
#define NA 1024
#define NO 10000
#define NL 128
#define NOL 129
#define NROWS (NB*NOL)   /* 2064 */
#define TOK_SOS 9999
#define TOK_EOS 9999
#define NBLK 256
#define NGW 64           /* gate-GEMM workgroups */

typedef unsigned short u16;
typedef unsigned int u32;
typedef unsigned long long u64;
typedef __bf16 bf16x8 __attribute__((ext_vector_type(8)));
typedef float f32x4 __attribute__((ext_vector_type(4)));
typedef unsigned short u16x8 __attribute__((ext_vector_type(8)));
typedef unsigned short u16x4 __attribute__((ext_vector_type(4)));

__device__ __forceinline__ float sigf(float x){ return 1.0f/(1.0f+expf(-x)); }
__device__ __forceinline__ float b2f(u16 s){
  union { u32 i; float f; } u; u.i = ((u32)s) << 16; return u.f;
}
__device__ __forceinline__ u16 f2b(float f){
  union { float f; u32 i; } u; u.f = f;
  u32 r = u.i + 0x7FFFu + ((u.i >> 16) & 1u);
  return (u16)(r >> 16);
}
__device__ __forceinline__ bf16x8 cvt8(float4 a, float4 b){
  union { u16 u[8]; bf16x8 v; } c;
  c.u[0]=f2b(a.x); c.u[1]=f2b(a.y); c.u[2]=f2b(a.z); c.u[3]=f2b(a.w);
  c.u[4]=f2b(b.x); c.u[5]=f2b(b.y); c.u[6]=f2b(b.z); c.u[7]=f2b(b.w);
  return c.v;
}
__device__ __forceinline__ bf16x8 zero8(){
  union { u16 u[8]; bf16x8 v; } c;
  #pragma unroll
  for (int i=0;i<8;++i) c.u[i]=0;
  return c.v;
}

// ---- coherent ops: SAME compiler-emitted policy that passed in round 5, but 8B wide ----
__device__ __forceinline__ void coh_stf(float* p, float v){
  __hip_atomic_store(p, v, __ATOMIC_RELAXED, __HIP_MEMORY_SCOPE_AGENT);
}
__device__ __forceinline__ u32 coh_ldu(const u32* p){
  return __hip_atomic_load((u32*)p, __ATOMIC_RELAXED, __HIP_MEMORY_SCOPE_AGENT);
}
__device__ __forceinline__ void coh_stu(u32* p, u32 v){
  __hip_atomic_store(p, v, __ATOMIC_RELAXED, __HIP_MEMORY_SCOPE_AGENT);
}
__device__ __forceinline__ u64 coh_ld64(const void* p){
  return __hip_atomic_load((const u64*)p, __ATOMIC_RELAXED, __HIP_MEMORY_SCOPE_AGENT);
}

// stage 32KB global->LDS via u64 coherent loads (256 thr x 16), conflict-free LDS writes
__device__ __forceinline__ void stage32(const char* g, char* l, int tid){
  u64 v[16];
  #pragma unroll
  for (int i=0;i<16;++i) v[i] = coh_ld64(g + i*2048 + tid*8);
  #pragma unroll
  for (int i=0;i<16;++i) *(u64*)(l + i*2048 + tid*8) = v[i];
}

// z/attc swizzle: u16-unit offset of element (b, d) in a [16][1024] buffer
__device__ __forceinline__ int zswz(int b, int d){
  return b*1024 + ((((d)>>3) ^ (b&7)) << 3) + (d&7);
}
// LDS fragment read (un-swizzled): 8 u16 = elems [blk*8 .. blk*8+7] of row
__device__ __forceinline__ bf16x8 lds_frag(const u16* s, int row, int blk){
  return *(const bf16x8*)(s + row*1024 + ((blk ^ (row&7)) << 3));
}

// ---------------- zero ----------------
__global__ void zero4_kernel(uint4* __restrict__ p, int n){
  int i = blockIdx.x*256 + threadIdx.x;
  if (i < n) p[i] = make_uint4(0,0,0,0);
}

// ---------------- f32 [4096][ld] (col slice) -> bf16 [4096][1024] ----------------
__global__ __launch_bounds__(256) void cvt_nk_kernel(
    const float* __restrict__ src, int ld, int off, u16* __restrict__ dst){
  int i = (blockIdx.x*256 + threadIdx.x)*4;
  int row = i >> 10, col = i & 1023;
  float4 v = *(const float4*)(src + (size_t)row*ld + off + col);
  u16x4 o = { f2b(v.x), f2b(v.y), f2b(v.z), f2b(v.w) };
  *(u16x4*)(dst + i) = o;
}

// ---------------- transpose-convert: src f32 [R][C] -> dst bf16 [C'][R] ----------------
__global__ __launch_bounds__(256) void tcvt_kernel(
    const float* __restrict__ src, int R, int C, u16* __restrict__ dst){
  __shared__ float tile[32][33];
  const int c0 = blockIdx.x*32, r0 = blockIdx.y*32;
  const int tx = threadIdx.x & 31, ty = threadIdx.x >> 5;
  #pragma unroll
  for (int k = 0; k < 4; ++k){
    int rr = ty + k*8;
    int c = c0 + tx;
    float v = (c < C) ? src[(size_t)(r0+rr)*C + c] : 0.0f;
    tile[rr][tx] = v;
  }
  __syncthreads();
  #pragma unroll
  for (int k = 0; k < 4; ++k){
    int cc = ty + k*8;
    dst[(size_t)(c0+cc)*R + r0 + tx] = f2b(tile[tx][cc]);
  }
}

// ---------------- hpad [16][512][1024] f32 -> masked bf16 transposed [16][1024][512] -------
__global__ __launch_bounds__(256) void hpadT_kernel(
    const float* __restrict__ hpad, const int* __restrict__ hlen, u16* __restrict__ dst){
  __shared__ float tile[32][33];
  const int e0 = blockIdx.x*32, t0 = blockIdx.y*32, b = blockIdx.z;
  const int tx = threadIdx.x & 31, ty = threadIdx.x >> 5;
  const int len = hlen[b];
  #pragma unroll
  for (int k = 0; k < 4; ++k){
    int r = ty + k*8;
    tile[r][tx] = hpad[((size_t)b*512 + t0 + r)*1024 + e0 + tx];
  }
  __syncthreads();
  #pragma unroll
  for (int k = 0; k < 4; ++k){
    int el = ty + k*8;
    float m = (t0 + tx < len) ? 1.0f : 0.0f;
    dst[((size_t)b*1024 + e0 + el)*512 + t0 + tx] = f2b(tile[tx][el]*m);
  }
}

// ---------------- bias1 = bih1 + bhh1 ----------------
__global__ void bias_add_kernel(const float* __restrict__ a, const float* __restrict__ b,
                                float* __restrict__ o){
  int i = blockIdx.x*256 + threadIdx.x;
  if (i < 4096) o[i] = a[i] + b[i];
}

// ---------------- pre_enc = tanh(mask(hpad) @ Wenc) via MFMA -> bf16 [8192][1024] ----------
__global__ __launch_bounds__(256) void preenc_mfma(
    const float* __restrict__ hpad, const int* __restrict__ hlen,
    const u16* __restrict__ wencT, u16* __restrict__ pre){
  const int m0 = blockIdx.x*64, n0 = blockIdx.y*64;
  const int tid = threadIdx.x, lane = tid & 63, wv = tid >> 6;
  const int r = lane & 15, q = lane >> 4;
  const int ar = m0 + wv*16 + r;
  const bool on = (ar & 511) < hlen[ar >> 9];
  const float* ap = hpad + (size_t)ar*1024 + q*8;
  f32x4 acc[4] = {{0,0,0,0},{0,0,0,0},{0,0,0,0},{0,0,0,0}};
  for (int kt = 0; kt < 32; ++kt){
    bf16x8 a;
    if (on){
      float4 v0 = *(const float4*)(ap + kt*32);
      float4 v1 = *(const float4*)(ap + kt*32 + 4);
      a = cvt8(v0, v1);
    } else a = zero8();
    #pragma unroll
    for (int s = 0; s < 4; ++s){
      const u16* bp = wencT + (size_t)(n0 + s*16 + r)*1024 + kt*32 + q*8;
      acc[s] = __builtin_amdgcn_mfma_f32_16x16x32_bf16(a, *(const bf16x8*)bp, acc[s], 0,0,0);
    }
  }
  #pragma unroll
  for (int s = 0; s < 4; ++s)
    #pragma unroll
    for (int rr = 0; rr < 4; ++rr){
      int row = m0 + wv*16 + q*4 + rr, col = n0 + s*16 + r;
      pre[(size_t)row*1024 + col] = f2b(tanhf(acc[s][rr]));
    }
}

// ---------------- gey = embed[ys_in] @ Wih0[:,0:1024]^T + bih0 + bhh0 via MFMA -> bf16 -----
__global__ __launch_bounds__(256) void gey_mfma(
    const int* __restrict__ ys, const float* __restrict__ embed,
    const float* __restrict__ Wih0, const float* __restrict__ bih0,
    const float* __restrict__ bhh0, u16* __restrict__ gey){
  const int m0 = blockIdx.x*64, n0 = blockIdx.y*64;
  const int tid = threadIdx.x, lane = tid & 63, wv = tid >> 6;
  const int r = lane & 15, q = lane >> 4;
  const int ar = m0 + wv*16 + r;
  int tok = 0;
  if (ar < NROWS){
    int bb = ar / NOL, l = ar - bb*NOL;
    tok = (l==0) ? TOK_SOS : ys[bb*NL + l - 1];
  }
  const float* ap = embed + (size_t)tok*1024 + q*8;
  f32x4 acc[4] = {{0,0,0,0},{0,0,0,0},{0,0,0,0},{0,0,0,0}};
  for (int kt = 0; kt < 32; ++kt){
    float4 v0 = *(const float4*)(ap + kt*32);
    float4 v1 = *(const float4*)(ap + kt*32 + 4);
    bf16x8 a = cvt8(v0, v1);
    #pragma unroll
    for (int s = 0; s < 4; ++s){
      const float* bp = Wih0 + (size_t)(n0 + s*16 + r)*2048 + kt*32 + q*8;
      float4 w0 = *(const float4*)(bp);
      float4 w1 = *(const float4*)(bp + 4);
      acc[s] = __builtin_amdgcn_mfma_f32_16x16x32_bf16(a, cvt8(w0,w1), acc[s], 0,0,0);
    }
  }
  #pragma unroll
  for (int s = 0; s < 4; ++s)
    #pragma unroll
    for (int rr = 0; rr < 4; ++rr){
      int row = m0 + wv*16 + q*4 + rr, col = n0 + s*16 + r;
      if (row < NROWS)
        gey[(size_t)row*4096 + col] = f2b(acc[s][rr] + bih0[col] + bhh0[col]);
    }
}

// ---------------- logits = zallb @ woutT^T + bout via MFMA -> bf16 [2064][10000] -----------
__global__ __launch_bounds__(256) void logits_mfma(
    const u16* __restrict__ zallb, const u16* __restrict__ woutT,
    const float* __restrict__ bout, u16* __restrict__ logits){
  const int m0 = blockIdx.x*64, n0 = blockIdx.y*64;
  const int tid = threadIdx.x, lane = tid & 63, wv = tid >> 6;
  const int r = lane & 15, q = lane >> 4;
  const int ar = m0 + wv*16 + r;
  const u16* ap = zallb + (size_t)ar*1024 + q*8;
  f32x4 acc[4] = {{0,0,0,0},{0,0,0,0},{0,0,0,0},{0,0,0,0}};
  for (int kt = 0; kt < 32; ++kt){
    bf16x8 a = *(const bf16x8*)(ap + kt*32);
    #pragma unroll
    for (int s = 0; s < 4; ++s){
      const u16* bp = woutT + (size_t)(n0 + s*16 + r)*1024 + kt*32 + q*8;
      acc[s] = __builtin_amdgcn_mfma_f32_16x16x32_bf16(a, *(const bf16x8*)bp, acc[s], 0,0,0);
    }
  }
  #pragma unroll
  for (int s = 0; s < 4; ++s)
    #pragma unroll
    for (int rr = 0; rr < 4; ++rr){
      int row = m0 + wv*16 + q*4 + rr, col = n0 + s*16 + r;
      if (row < NROWS && col < NO)
        logits[(size_t)row*NO + col] = f2b(acc[s][rr] + bout[col]);
    }
}

// ---------------- round-5 flag/broadcast grid barrier (1 poller/WG, no fences) -------------
__device__ __forceinline__ void gbar(u32* af, int epoch){
  __syncthreads();
  if (blockIdx.x == 0){
    int w = threadIdx.x;
    if (w > 0){
      while (coh_ldu(&af[w << 5]) < (u32)epoch) __builtin_amdgcn_s_sleep(1);
    }
    __syncthreads();
    if (threadIdx.x == 0) coh_stu(&af[0], (u32)epoch);
  } else {
    if (threadIdx.x == 0){
      coh_stu(&af[blockIdx.x << 5], (u32)epoch);
      while (coh_ldu(&af[0]) < (u32)epoch) __builtin_amdgcn_s_sleep(1);
    }
    __syncthreads();
  }
}

// ---------------- persistent sequential kernel ----------------
// 256 WGs; WGs 0..63 are gate-WGs (wave = gate, WG owns d = wg*16..+15).
__global__ __launch_bounds__(256, 1) void seq_kernel(
    const u16* __restrict__ pre,    // [8192][1024] bf16 (cached)
    const u16* __restrict__ hpadT,  // [16][1024][512] bf16 masked (cached)
    const u16* __restrict__ w0c,    // [4096][1024] Wih0[:,1024:] bf16 (cached)
    const u16* __restrict__ wh0,    // [4096][1024] (cached)
    const u16* __restrict__ w1c,    // [4096][1024] (cached)
    const u16* __restrict__ wh1,    // [4096][1024] (cached)
    const u16* __restrict__ wdecT,  // [1024 n][1024 k] bf16 (cached)
    const u16* __restrict__ gey,    // [2064][4096] bf16 (cached)
    const float* __restrict__ bias1,// [4096] (cached)
    const int* __restrict__ hlen,
    float* dqf,                     // [16][1024] f32 (coherent)
    float* esc,                     // [16][512] f32 (coherent)
    u16* attc,                      // [16][1024] bf16 swizzled (coherent)
    u16* z0bf, u16* z1bf,           // [2][16][1024] bf16 swizzled ping-pong (coherent)
    u16* zallb,                     // [2112][1024] bf16 (normal stores)
    u32* af)
{
  const int wg = blockIdx.x, tid = threadIdx.x;
  const int lane = tid & 63, wv = tid >> 6;
  const int r = lane & 15, q = lane >> 4;

  extern __shared__ __align__(16) char dynlds[];
  u16*   sZ0  = (u16*)dynlds;              // 32KB
  u16*   sZ1  = (u16*)(dynlds + 32768);    // 32KB (aliased as sAt in phase D)
  float* sDq  = (float*)(dynlds + 65536);  // 4KB
  float* sEsc = (float*)(dynlds + 69632);  // 2KB
  u16*   sAt  = sZ1;
  __shared__ float gex[4][16][16];
  __shared__ float sred[256];
  __shared__ float sw[512];
  __shared__ float spart[4][64];

  float c0r = 0.f, c1r = 0.f;   // cell state for (b=tid>>4, d=wg*16+(tid&15)) in gate-WGs
  int epoch = 1;

  for (int t = 0; t <= NOL; ++t){
    const int cur = t & 1, prv = cur ^ 1;

    // ======== Phase A (gate-WGs): gemm1+cell1(t-1), dq(t) ========
    if (wg < NGW){
      stage32((const char*)(z0bf + prv*16384), (char*)sZ0, tid);
      stage32((const char*)(z1bf + cur*16384), (char*)sZ1, tid);
      __syncthreads();
      if (t >= 1){
        const int s = t - 1;
        f32x4 acc = {0.f,0.f,0.f,0.f};
        const u16* B1 = w1c + (size_t)(wv*1024 + wg*16 + r)*1024 + q*8;
        const u16* B2 = wh1 + (size_t)(wv*1024 + wg*16 + r)*1024 + q*8;
        #pragma unroll 8
        for (int kt = 0; kt < 32; ++kt)
          acc = __builtin_amdgcn_mfma_f32_16x16x32_bf16(
                  lds_frag(sZ0, r, kt*4+q), *(const bf16x8*)(B1 + kt*32), acc, 0,0,0);
        #pragma unroll 8
        for (int kt = 0; kt < 32; ++kt)
          acc = __builtin_amdgcn_mfma_f32_16x16x32_bf16(
                  lds_frag(sZ1, r, kt*4+q), *(const bf16x8*)(B2 + kt*32), acc, 0,0,0);
        #pragma unroll
        for (int rr = 0; rr < 4; ++rr) gex[wv][q*4+rr][r] = acc[rr];
        __syncthreads();
        {
          int b = tid >> 4, dd = tid & 15, d = wg*16 + dd;
          float g0 = gex[0][b][dd] + bias1[d];
          float g1 = gex[1][b][dd] + bias1[1024 + d];
          float g2 = gex[2][b][dd] + bias1[2048 + d];
          float g3 = gex[3][b][dd] + bias1[3072 + d];
          float cn = sigf(g1)*c1r + sigf(g0)*tanhf(g2);
          float zn = sigf(g3)*tanhf(cn);
          c1r = cn;
          float zn2 = __shfl_down(zn, 1);
          if ((tid & 1) == 0){
            u32 pk = (u32)f2b(zn) | ((u32)f2b(zn2) << 16);
            *(u32*)(zallb + ((size_t)b*NOL + s)*1024 + d) = pk;       // normal store
            coh_stu((u32*)(z1bf + prv*16384 + zswz(b, d)), pk);
          }
        }
        __syncthreads();   // gex reuse below
      }
      if (t < NOL){
        f32x4 acc = {0.f,0.f,0.f,0.f};
        const u16* Bd = wdecT + (size_t)(wg*16 + r)*1024 + q*8;
        #pragma unroll
        for (int i = 0; i < 8; ++i){
          int kt = wv*8 + i;
          acc = __builtin_amdgcn_mfma_f32_16x16x32_bf16(
                  lds_frag(sZ0, r, kt*4+q), *(const bf16x8*)(Bd + kt*32), acc, 0,0,0);
        }
        #pragma unroll
        for (int rr = 0; rr < 4; ++rr) gex[wv][q*4+rr][r] = acc[rr];
        __syncthreads();
        {
          int b = tid >> 4, j = tid & 15;
          float s2 = gex[0][b][j] + gex[1][b][j] + gex[2][b][j] + gex[3][b][j];
          coh_stf(&dqf[b*1024 + wg*16 + j], tanhf(s2));
        }
      }
    }
    gbar(af, epoch++);
    if (t == NOL) break;

    // ======== Phase B: escore = 2 * pre . dq  (all 256 WGs, 32 rows each) ========
    {
      const int b = wg >> 4;
      { const char* gq = (const char*)(dqf + b*1024);
        u64 v0 = coh_ld64(gq + tid*8);
        u64 v1 = coh_ld64(gq + 2048 + tid*8);
        *(u64*)((char*)sDq + tid*8) = v0;
        *(u64*)((char*)sDq + 2048 + tid*8) = v1; }
      __syncthreads();
      const int rbase = wg*32 + wv*8;
      float qv[16];
      #pragma unroll
      for (int i = 0; i < 4; ++i)
        *(float4*)(qv + i*4) = *(const float4*)(sDq + lane*16 + i*4);
      #pragma unroll
      for (int rr = 0; rr < 8; ++rr){
        const u16* pr = pre + (size_t)(rbase+rr)*1024 + lane*16;
        u16x8 p0 = *(const u16x8*)(pr);
        u16x8 p1 = *(const u16x8*)(pr+8);
        float acc = 0.f;
        #pragma unroll
        for (int j = 0; j < 8; ++j){
          acc += b2f(p0[j])*qv[j];
          acc += b2f(p1[j])*qv[8+j];
        }
        #pragma unroll
        for (int off = 32; off > 0; off >>= 1) acc += __shfl_xor(acc, off, 64);
        if (lane == 0) coh_stf(&esc[rbase+rr], 2.0f*acc);
      }
    }
    gbar(af, epoch++);

    // ======== Phase C: softmax + att_c (b = wg>>4, 64-col e-slice) ========
    {
      const int b = wg >> 4, ec = wg & 15;
      { u64 v = coh_ld64((const char*)(esc + b*512) + tid*8);
        *(u64*)((char*)sEsc + tid*8) = v; }
      __syncthreads();
      const int len = hlen[b];
      float e0 = (tid < len)     ? sEsc[tid]       : -INFINITY;
      float e1 = (tid+256 < len) ? sEsc[tid + 256] : -INFINITY;
      sred[tid] = fmaxf(e0, e1);
      __syncthreads();
      #pragma unroll
      for (int s2 = 128; s2 > 0; s2 >>= 1){
        if (tid < s2) sred[tid] = fmaxf(sred[tid], sred[tid+s2]);
        __syncthreads();
      }
      float mx = sred[0];
      __syncthreads();
      float p0 = (tid < len)     ? expf(e0 - mx) : 0.0f;
      float p1 = (tid+256 < len) ? expf(e1 - mx) : 0.0f;
      sred[tid] = p0 + p1;
      __syncthreads();
      #pragma unroll
      for (int s2 = 128; s2 > 0; s2 >>= 1){
        if (tid < s2) sred[tid] += sred[tid+s2];
        __syncthreads();
      }
      float inv = 1.0f/sred[0];
      sw[tid] = p0*inv; sw[tid+256] = p1*inv;
      __syncthreads();
      const int el = tid & 63, th = tid >> 6;
      const u16* hp = hpadT + ((size_t)b*1024 + ec*64 + el)*512 + th*128;
      float acc = 0.f;
      #pragma unroll
      for (int i = 0; i < 16; ++i){
        u16x8 v = *(const u16x8*)(hp + i*8);
        #pragma unroll
        for (int j = 0; j < 8; ++j) acc += sw[th*128 + i*8 + j]*b2f(v[j]);
      }
      spart[th][el] = acc;
      __syncthreads();
      if (tid < 64){
        float s2 = spart[0][tid]+spart[1][tid]+spart[2][tid]+spart[3][tid];
        float s2n = __shfl_down(s2, 1);
        if ((tid & 1) == 0){
          int e = ec*64 + tid;
          u32 pk = (u32)f2b(s2) | ((u32)f2b(s2n) << 16);
          coh_stu((u32*)(attc + zswz(b, e)), pk);
        }
      }
    }
    gbar(af, epoch++);

    // ======== Phase D (gate-WGs): gemm0 + cell0(t) -> z0(t) ========
    if (wg < NGW){
      stage32((const char*)attc, (char*)sAt, tid);
      __syncthreads();
      f32x4 acc = {0.f,0.f,0.f,0.f};
      const u16* B1 = w0c + (size_t)(wv*1024 + wg*16 + r)*1024 + q*8;
      const u16* B2 = wh0 + (size_t)(wv*1024 + wg*16 + r)*1024 + q*8;
      #pragma unroll 8
      for (int kt = 0; kt < 32; ++kt)
        acc = __builtin_amdgcn_mfma_f32_16x16x32_bf16(
                lds_frag(sAt, r, kt*4+q), *(const bf16x8*)(B1 + kt*32), acc, 0,0,0);
      #pragma unroll 8
      for (int kt = 0; kt < 32; ++kt)
        acc = __builtin_amdgcn_mfma_f32_16x16x32_bf16(
                lds_frag(sZ0, r, kt*4+q), *(const bf16x8*)(B2 + kt*32), acc, 0,0,0);
      #pragma unroll
      for (int rr = 0; rr < 4; ++rr) gex[wv][q*4+rr][r] = acc[rr];
      __syncthreads();
      {
        int b = tid >> 4, dd = tid & 15, d = wg*16 + dd;
        const u16* gr = gey + ((size_t)b*NOL + t)*4096 + d;
        float g0 = gex[0][b][dd] + b2f(gr[0]);
        float g1 = gex[1][b][dd] + b2f(gr[1024]);
        float g2 = gex[2][b][dd] + b2f(gr[2048]);
        float g3 = gex[3][b][dd] + b2f(gr[3072]);
        float cn = sigf(g1)*c0r + sigf(g0)*tanhf(g2);
        float zn = sigf(g3)*tanhf(cn);
        c0r = cn;
        float zn2 = __shfl_down(zn, 1);
        if ((tid & 1) == 0){
          u32 pk = (u32)f2b(zn) | ((u32)f2b(zn2) << 16);
          coh_stu((u32*)(z0bf + cur*16384 + zswz(b, d)), pk);
        }
      }
    }
    gbar(af, epoch++);
  }
}

// ---------------- per-row log_softmax + NLL + argmax (bf16 logits) ----------------
__global__ __launch_bounds__(256) void loss_kernel(
    const u16* __restrict__ logits, const int* __restrict__ ys, float* __restrict__ accum){
  int row = blockIdx.x;
  int tid = threadIdx.x;
  const u16* lr = logits + (size_t)row * NO;
  __shared__ float sv[256];
  __shared__ int   si[256];
  float mx = -INFINITY; int mi = 0;
  for (int n = tid; n < NO; n += 256){
    float v = b2f(lr[n]);
    if (v > mx){ mx = v; mi = n; }
  }
  sv[tid] = mx; si[tid] = mi;
  __syncthreads();
  for (int s=128; s>0; s>>=1){
    if (tid < s){
      if (sv[tid+s] > sv[tid] || (sv[tid+s]==sv[tid] && si[tid+s] < si[tid])){
        sv[tid] = sv[tid+s]; si[tid] = si[tid+s];
      }
    }
    __syncthreads();
  }
  float gmx = sv[0]; int gmi = si[0];
  __syncthreads();
  float ps = 0.0f;
  for (int n = tid; n < NO; n += 256) ps += expf(b2f(lr[n])-gmx);
  sv[tid] = ps;
  __syncthreads();
  for (int s=128; s>0; s>>=1){ if (tid<s) sv[tid] += sv[tid+s]; __syncthreads(); }
  if (tid==0){
    int b = row / NOL, l = row - b*NOL;
    int label = (l < NL) ? ys[b*NL + l] : TOK_EOS;
    float lse = gmx + logf(sv[0]);
    float nll = lse - b2f(lr[label]);
    atomicAdd(&accum[0], nll);
    atomicAdd(&accum[1], (gmi==label) ? 1.0f : 0.0f);
  }
}

__global__ void finalize_kernel(const float* __restrict__ accum, float* __restrict__ out){
  out[0] = accum[0] / (float)NROWS * (float)(NOL-1);
  out[1] = accum[1] / (float)NROWS;
}

extern "C" void kernel_launch(void* const* d_in, const int* in_sizes, int n_in,
                              void* d_out, int out_size, void* d_ws, size_t ws_size,
                              hipStream_t stream){
  const float* hpad  = (const float*)d_in[0];
  const int*   hlen  = (const int*)  d_in[1];
  const int*   ys    = (const int*)  d_in[2];
  const float* embed = (const float*)d_in[3];
  const float* Wenc  = (const float*)d_in[4];
  const float* Wdec  = (const float*)d_in[5];
  const float* Wih0  = (const float*)d_in[6];
  const float* Whh0  = (const float*)d_in[7];
  const float* bih0  = (const float*)d_in[8];
  const float* bhh0  = (const float*)d_in[9];
  const float* Wih1  = (const float*)d_in[10];
  const float* Whh1  = (const float*)d_in[11];
  const float* bih1  = (const float*)d_in[12];
  const float* bhh1  = (const float*)d_in[13];
  const float* Wout  = (const float*)d_in[14];
  const float* bout  = (const float*)d_in[15];
  float* out = (float*)d_out;

  char* ws = (char*)d_ws;
  size_t cur = 0;
  auto alloc = [&](size_t bytes) -> char* {
    char* p = ws + cur;
    cur += (bytes + 255) & ~(size_t)255;
    return p;
  };
  u16*   pre_bf   = (u16*)  alloc(16777216);   // [8192][1024]
  u16*   hpadT    = (u16*)  alloc(16777216);   // [16][1024][512]
  u16*   w0c      = (u16*)  alloc(8388608);    // Wih0[:,1024:]
  u16*   wh0      = (u16*)  alloc(8388608);
  u16*   w1c      = (u16*)  alloc(8388608);
  u16*   wh1      = (u16*)  alloc(8388608);
  u16*   wdecT    = (u16*)  alloc(2097152);    // [1024][1024]
  u16*   wencT    = (u16*)  alloc(2097152);    // [1024][1024]
  u16*   woutT    = (u16*)  alloc(20578304);   // [10048][1024]
  u16*   gey      = (u16*)  alloc(16908288);   // [2064][4096]
  u16*   zallb    = (u16*)  alloc(4325376);    // [2112][1024]
  u16*   logits   = (u16*)  alloc(41280000);   // [2064][10000]
  float* dqf      = (float*)alloc(65536);
  float* esc      = (float*)alloc(32768);
  u16*   attc     = (u16*)  alloc(32768);
  float* bias1    = (float*)alloc(16384);
  // ---- zeroed region (contiguous) ----
  u32*   af       = (u32*)  alloc(32768);      // 256 WGs x 128B; af[0] = go word
  u16*   z0bf     = (u16*)  alloc(65536);      // [2][16][1024]
  u16*   z1bf     = (u16*)  alloc(65536);
  float* accum    = (float*)alloc(128);
  // zero bytes = 32768 + 65536 + 65536 + 128 = 163968 -> 10248 uint4
  zero4_kernel<<<41, 256, 0, stream>>>((uint4*)af, 10248);

  tcvt_kernel<<<dim3(32,32),  256, 0, stream>>>(Wenc, 1024, 1024, wencT);
  tcvt_kernel<<<dim3(32,32),  256, 0, stream>>>(Wdec, 1024, 1024, wdecT);
  tcvt_kernel<<<dim3(313,32), 256, 0, stream>>>(Wout, 1024, NO,   woutT);
  cvt_nk_kernel<<<4096, 256, 0, stream>>>(Wih0, 2048, 1024, w0c);
  cvt_nk_kernel<<<4096, 256, 0, stream>>>(Whh0, 1024, 0, wh0);
  cvt_nk_kernel<<<4096, 256, 0, stream>>>(Wih1, 1024, 0, w1c);
  cvt_nk_kernel<<<4096, 256, 0, stream>>>(Whh1, 1024, 0, wh1);
  hpadT_kernel<<<dim3(32,16,16), 256, 0, stream>>>(hpad, hlen, hpadT);
  bias_add_kernel<<<16, 256, 0, stream>>>(bih1, bhh1, bias1);
  preenc_mfma<<<dim3(128,16), 256, 0, stream>>>(hpad, hlen, wencT, pre_bf);
  gey_mfma<<<dim3(33,64), 256, 0, stream>>>(ys, embed, Wih0, bih0, bhh0, gey);

  hipFuncSetAttribute((const void*)seq_kernel,
                      hipFuncAttributeMaxDynamicSharedMemorySize, 71680);
  seq_kernel<<<NBLK, 256, 71680, stream>>>(pre_bf, hpadT, w0c, wh0, w1c, wh1,
                                           wdecT, gey, bias1, hlen, dqf, esc, attc,
                                           z0bf, z1bf, zallb, af);

  logits_mfma<<<dim3(33,157), 256, 0, stream>>>(zallb, woutT, bout, logits);
  loss_kernel<<<NROWS, 256, 0, stream>>>(logits, ys, accum);
  finalize_kernel<<<1, 1, 0, stream>>>(accum, out);
}

// Round 10
// 6608.607 us; speedup vs baseline: 1.2493x; 1.0194x over previous
//
#include <hip/hip_runtime.h>
#include <math.h>

#define NB 16
#define NT 512
#define NE 1024
#define ND 1024
#define NA 1024
#define NO 10000
#define NL 128
#define NOL 129
#define NROWS (NB*NOL)   /* 2064 */
#define TOK_SOS 9999
#define TOK_EOS 9999
#define NBLK 64          /* seq workgroups (all are gate-WGs) */

typedef unsigned short u16;
typedef unsigned int u32;
typedef unsigned long long u64;
typedef __bf16 bf16x8 __attribute__((ext_vector_type(8)));
typedef float f32x4 __attribute__((ext_vector_type(4)));
typedef unsigned short u16x8 __attribute__((ext_vector_type(8)));
typedef unsigned short u16x4 __attribute__((ext_vector_type(4)));

__device__ __forceinline__ float sigf(float x){ return 1.0f/(1.0f+expf(-x)); }
__device__ __forceinline__ float b2f(u16 s){
  union { u32 i; float f; } u; u.i = ((u32)s) << 16; return u.f;
}
__device__ __forceinline__ u16 f2b(float f){
  union { float f; u32 i; } u; u.f = f;
  u32 r = u.i + 0x7FFFu + ((u.i >> 16) & 1u);
  return (u16)(r >> 16);
}
__device__ __forceinline__ bf16x8 cvt8(float4 a, float4 b){
  union { u16 u[8]; bf16x8 v; } c;
  c.u[0]=f2b(a.x); c.u[1]=f2b(a.y); c.u[2]=f2b(a.z); c.u[3]=f2b(a.w);
  c.u[4]=f2b(b.x); c.u[5]=f2b(b.y); c.u[6]=f2b(b.z); c.u[7]=f2b(b.w);
  return c.v;
}
__device__ __forceinline__ bf16x8 zero8(){
  union { u16 u[8]; bf16x8 v; } c;
  #pragma unroll
  for (int i=0;i<8;++i) c.u[i]=0;
  return c.v;
}

// ---- coherent ops (compiler-emitted agent-relaxed policy; proven r5/r9) ----
__device__ __forceinline__ void coh_stf(float* p, float v){
  __hip_atomic_store(p, v, __ATOMIC_RELAXED, __HIP_MEMORY_SCOPE_AGENT);
}
__device__ __forceinline__ u32 coh_ldu(const u32* p){
  return __hip_atomic_load((u32*)p, __ATOMIC_RELAXED, __HIP_MEMORY_SCOPE_AGENT);
}
__device__ __forceinline__ void coh_stu(u32* p, u32 v){
  __hip_atomic_store(p, v, __ATOMIC_RELAXED, __HIP_MEMORY_SCOPE_AGENT);
}
__device__ __forceinline__ u64 coh_ld64(const void* p){
  return __hip_atomic_load((const u64*)p, __ATOMIC_RELAXED, __HIP_MEMORY_SCOPE_AGENT);
}

// stage 32KB global->LDS via u64 coherent loads (512 thr x 8), conflict-free LDS writes
__device__ __forceinline__ void stage32(const char* g, char* l, int tid){
  u64 v[8];
  #pragma unroll
  for (int i=0;i<8;++i) v[i] = coh_ld64(g + i*4096 + tid*8);
  #pragma unroll
  for (int i=0;i<8;++i) *(u64*)(l + i*4096 + tid*8) = v[i];
}

// z/attc swizzle: u16-unit offset of element (b, d) in a [16][1024] buffer
__device__ __forceinline__ int zswz(int b, int d){
  return b*1024 + ((((d)>>3) ^ (b&7)) << 3) + (d&7);
}
// LDS fragment read (un-swizzled): 8 u16 = elems [blk*8 .. blk*8+7] of row
__device__ __forceinline__ bf16x8 lds_frag(const u16* s, int row, int blk){
  return *(const bf16x8*)(s + row*1024 + ((blk ^ (row&7)) << 3));
}

// ---- one-hop all-poll barrier: arrive (flag store) ... [prefetch] ... wait (poll all) ----
__device__ __forceinline__ void bar_arrive(u32* af, int epoch){
  __syncthreads();   // drains each thread's payload stores before any thread's flag
  if (threadIdx.x == 0) coh_stu(&af[blockIdx.x << 7], (u32)epoch);
}
__device__ __forceinline__ void bar_wait(u32* af, int epoch){
  if ((int)threadIdx.x < NBLK){
    while ((int)coh_ldu(&af[threadIdx.x << 7]) < epoch) __builtin_amdgcn_s_sleep(4);
  }
  __syncthreads();
}

// ---------------- zero ----------------
__global__ void zero4_kernel(uint4* __restrict__ p, int n){
  int i = blockIdx.x*256 + threadIdx.x;
  if (i < n) p[i] = make_uint4(0,0,0,0);
}

// ---------------- f32 [4096][ld] (col slice) -> bf16 [4096][1024] ----------------
__global__ __launch_bounds__(256) void cvt_nk_kernel(
    const float* __restrict__ src, int ld, int off, u16* __restrict__ dst){
  int i = (blockIdx.x*256 + threadIdx.x)*4;
  int row = i >> 10, col = i & 1023;
  float4 v = *(const float4*)(src + (size_t)row*ld + off + col);
  u16x4 o = { f2b(v.x), f2b(v.y), f2b(v.z), f2b(v.w) };
  *(u16x4*)(dst + i) = o;
}

// ---------------- transpose-convert: src f32 [R][C] -> dst bf16 [C'][R] ----------------
__global__ __launch_bounds__(256) void tcvt_kernel(
    const float* __restrict__ src, int R, int C, u16* __restrict__ dst){
  __shared__ float tile[32][33];
  const int c0 = blockIdx.x*32, r0 = blockIdx.y*32;
  const int tx = threadIdx.x & 31, ty = threadIdx.x >> 5;
  #pragma unroll
  for (int k = 0; k < 4; ++k){
    int rr = ty + k*8;
    int c = c0 + tx;
    float v = (c < C) ? src[(size_t)(r0+rr)*C + c] : 0.0f;
    tile[rr][tx] = v;
  }
  __syncthreads();
  #pragma unroll
  for (int k = 0; k < 4; ++k){
    int cc = ty + k*8;
    dst[(size_t)(c0+cc)*R + r0 + tx] = f2b(tile[tx][cc]);
  }
}

// ---------------- hpad [16][512][1024] f32 -> masked bf16 transposed [16][1024][512] -------
__global__ __launch_bounds__(256) void hpadT_kernel(
    const float* __restrict__ hpad, const int* __restrict__ hlen, u16* __restrict__ dst){
  __shared__ float tile[32][33];
  const int e0 = blockIdx.x*32, t0 = blockIdx.y*32, b = blockIdx.z;
  const int tx = threadIdx.x & 31, ty = threadIdx.x >> 5;
  const int len = hlen[b];
  #pragma unroll
  for (int k = 0; k < 4; ++k){
    int r = ty + k*8;
    tile[r][tx] = hpad[((size_t)b*512 + t0 + r)*1024 + e0 + tx];
  }
  __syncthreads();
  #pragma unroll
  for (int k = 0; k < 4; ++k){
    int el = ty + k*8;
    float m = (t0 + tx < len) ? 1.0f : 0.0f;
    dst[((size_t)b*1024 + e0 + el)*512 + t0 + tx] = f2b(tile[tx][el]*m);
  }
}

// ---------------- bias1 = bih1 + bhh1 ----------------
__global__ void bias_add_kernel(const float* __restrict__ a, const float* __restrict__ b,
                                float* __restrict__ o){
  int i = blockIdx.x*256 + threadIdx.x;
  if (i < 4096) o[i] = a[i] + b[i];
}

// ---------------- pre_enc = tanh(mask(hpad) @ Wenc) via MFMA -> bf16 [8192][1024] ----------
__global__ __launch_bounds__(256) void preenc_mfma(
    const float* __restrict__ hpad, const int* __restrict__ hlen,
    const u16* __restrict__ wencT, u16* __restrict__ pre){
  const int m0 = blockIdx.x*64, n0 = blockIdx.y*64;
  const int tid = threadIdx.x, lane = tid & 63, wv = tid >> 6;
  const int r = lane & 15, q = lane >> 4;
  const int ar = m0 + wv*16 + r;
  const bool on = (ar & 511) < hlen[ar >> 9];
  const float* ap = hpad + (size_t)ar*1024 + q*8;
  f32x4 acc[4] = {{0,0,0,0},{0,0,0,0},{0,0,0,0},{0,0,0,0}};
  for (int kt = 0; kt < 32; ++kt){
    bf16x8 a;
    if (on){
      float4 v0 = *(const float4*)(ap + kt*32);
      float4 v1 = *(const float4*)(ap + kt*32 + 4);
      a = cvt8(v0, v1);
    } else a = zero8();
    #pragma unroll
    for (int s = 0; s < 4; ++s){
      const u16* bp = wencT + (size_t)(n0 + s*16 + r)*1024 + kt*32 + q*8;
      acc[s] = __builtin_amdgcn_mfma_f32_16x16x32_bf16(a, *(const bf16x8*)bp, acc[s], 0,0,0);
    }
  }
  #pragma unroll
  for (int s = 0; s < 4; ++s)
    #pragma unroll
    for (int rr = 0; rr < 4; ++rr){
      int row = m0 + wv*16 + q*4 + rr, col = n0 + s*16 + r;
      pre[(size_t)row*1024 + col] = f2b(tanhf(acc[s][rr]));
    }
}

// ---------------- gey = embed[ys_in] @ Wih0[:,0:1024]^T + bih0 + bhh0 via MFMA -> bf16 -----
__global__ __launch_bounds__(256) void gey_mfma(
    const int* __restrict__ ys, const float* __restrict__ embed,
    const float* __restrict__ Wih0, const float* __restrict__ bih0,
    const float* __restrict__ bhh0, u16* __restrict__ gey){
  const int m0 = blockIdx.x*64, n0 = blockIdx.y*64;
  const int tid = threadIdx.x, lane = tid & 63, wv = tid >> 6;
  const int r = lane & 15, q = lane >> 4;
  const int ar = m0 + wv*16 + r;
  int tok = 0;
  if (ar < NROWS){
    int bb = ar / NOL, l = ar - bb*NOL;
    tok = (l==0) ? TOK_SOS : ys[bb*NL + l - 1];
  }
  const float* ap = embed + (size_t)tok*1024 + q*8;
  f32x4 acc[4] = {{0,0,0,0},{0,0,0,0},{0,0,0,0},{0,0,0,0}};
  for (int kt = 0; kt < 32; ++kt){
    float4 v0 = *(const float4*)(ap + kt*32);
    float4 v1 = *(const float4*)(ap + kt*32 + 4);
    bf16x8 a = cvt8(v0, v1);
    #pragma unroll
    for (int s = 0; s < 4; ++s){
      const float* bp = Wih0 + (size_t)(n0 + s*16 + r)*2048 + kt*32 + q*8;
      float4 w0 = *(const float4*)(bp);
      float4 w1 = *(const float4*)(bp + 4);
      acc[s] = __builtin_amdgcn_mfma_f32_16x16x32_bf16(a, cvt8(w0,w1), acc[s], 0,0,0);
    }
  }
  #pragma unroll
  for (int s = 0; s < 4; ++s)
    #pragma unroll
    for (int rr = 0; rr < 4; ++rr){
      int row = m0 + wv*16 + q*4 + rr, col = n0 + s*16 + r;
      if (row < NROWS)
        gey[(size_t)row*4096 + col] = f2b(acc[s][rr] + bih0[col] + bhh0[col]);
    }
}

// ---------------- logits = zallb @ woutT^T + bout via MFMA -> bf16 [2064][10000] -----------
__global__ __launch_bounds__(256) void logits_mfma(
    const u16* __restrict__ zallb, const u16* __restrict__ woutT,
    const float* __restrict__ bout, u16* __restrict__ logits){
  const int m0 = blockIdx.x*64, n0 = blockIdx.y*64;
  const int tid = threadIdx.x, lane = tid & 63, wv = tid >> 6;
  const int r = lane & 15, q = lane >> 4;
  const int ar = m0 + wv*16 + r;
  const u16* ap = zallb + (size_t)ar*1024 + q*8;
  f32x4 acc[4] = {{0,0,0,0},{0,0,0,0},{0,0,0,0},{0,0,0,0}};
  for (int kt = 0; kt < 32; ++kt){
    bf16x8 a = *(const bf16x8*)(ap + kt*32);
    #pragma unroll
    for (int s = 0; s < 4; ++s){
      const u16* bp = woutT + (size_t)(n0 + s*16 + r)*1024 + kt*32 + q*8;
      acc[s] = __builtin_amdgcn_mfma_f32_16x16x32_bf16(a, *(const bf16x8*)bp, acc[s], 0,0,0);
    }
  }
  #pragma unroll
  for (int s = 0; s < 4; ++s)
    #pragma unroll
    for (int rr = 0; rr < 4; ++rr){
      int row = m0 + wv*16 + q*4 + rr, col = n0 + s*16 + r;
      if (row < NROWS && col < NO)
        logits[(size_t)row*NO + col] = f2b(acc[s][rr] + bout[col]);
    }
}

// ---------------- persistent sequential kernel: 64 WGs x 512 threads ----------------
// Each WG: gate d-slice wg*16..+15 (phases A/D), b=wg>>2 + chunk=wg&3 (phases B/C).
__global__ __launch_bounds__(512, 1) void seq_kernel(
    const u16* __restrict__ pre,    // [8192][1024] bf16 (cached)
    const u16* __restrict__ hpadT,  // [16][1024][512] bf16 masked (cached)
    const u16* __restrict__ w0c,    // [4096][1024] Wih0[:,1024:] bf16 (cached)
    const u16* __restrict__ wh0,    // [4096][1024] (cached)
    const u16* __restrict__ w1c,    // [4096][1024] (cached)
    const u16* __restrict__ wh1,    // [4096][1024] (cached)
    const u16* __restrict__ wdecT,  // [1024 n][1024 k] bf16 (cached)
    const u16* __restrict__ gey,    // [2064][4096] bf16 (cached)
    const float* __restrict__ bias1,// [4096] (cached)
    const int* __restrict__ hlen,
    float* dqf,                     // [16][1024] f32 (coherent)
    float* esc,                     // [16][512] f32 (coherent)
    u16* attc,                      // [16][1024] bf16 swizzled (coherent)
    u16* z0bf, u16* z1bf,           // [2][16][1024] bf16 swizzled ping-pong (coherent)
    u16* zallb,                     // [2112][1024] bf16 (normal stores)
    u32* af)
{
  const int wg = blockIdx.x, tid = threadIdx.x;
  const int lane = tid & 63, wv = tid >> 6;      // wv 0..7
  const int r = lane & 15, q = lane >> 4;
  const int g = wv >> 1, h = wv & 1;             // gate, K-half
  const int eb = wg >> 2, ch = wg & 3;           // b, chunk for B/C phases

  extern __shared__ __align__(16) char dynlds[];
  u16*   sZ0  = (u16*)dynlds;              // 32KB
  u16*   sZ1  = (u16*)(dynlds + 32768);    // 32KB (aliased as sAt in phase D)
  float* sDq  = (float*)(dynlds + 65536);  // 4KB
  float* sEsc = (float*)(dynlds + 69632);  // 2KB
  u16*   sAt  = sZ1;
  __shared__ float gex[8][16][16];
  __shared__ float sred[512];
  __shared__ float sw[512];
  __shared__ float spart[2][256];

  float c0r = 0.f, c1r = 0.f;   // cell state (tid<256: b=tid>>4, d=wg*16+(tid&15))
  int epoch = 1;
  const int len = hlen[eb];

  for (int t = 0; t <= NOL; ++t){
    const int cur = t & 1, prv = cur ^ 1;

    // ======== Phase A: gemm1+cell1(t-1), dq(t) ========
    stage32((const char*)(z0bf + prv*16384), (char*)sZ0, tid);
    stage32((const char*)(z1bf + cur*16384), (char*)sZ1, tid);
    __syncthreads();
    if (t >= 1){
      const int s = t - 1;
      f32x4 acc = {0.f,0.f,0.f,0.f};
      const u16* As = h ? sZ1 : sZ0;
      const u16* Bs = (h ? wh1 : w1c) + (size_t)(g*1024 + wg*16 + r)*1024 + q*8;
      #pragma unroll 8
      for (int kt = 0; kt < 32; ++kt)
        acc = __builtin_amdgcn_mfma_f32_16x16x32_bf16(
                lds_frag(As, r, kt*4+q), *(const bf16x8*)(Bs + kt*32), acc, 0,0,0);
      #pragma unroll
      for (int rr = 0; rr < 4; ++rr) gex[wv][q*4+rr][r] = acc[rr];
      __syncthreads();
      if (tid < 256){
        int b = tid >> 4, dd = tid & 15, d = wg*16 + dd;
        float g0 = gex[0][b][dd] + gex[1][b][dd] + bias1[d];
        float g1 = gex[2][b][dd] + gex[3][b][dd] + bias1[1024 + d];
        float g2 = gex[4][b][dd] + gex[5][b][dd] + bias1[2048 + d];
        float g3 = gex[6][b][dd] + gex[7][b][dd] + bias1[3072 + d];
        float cn = sigf(g1)*c1r + sigf(g0)*tanhf(g2);
        float zn = sigf(g3)*tanhf(cn);
        c1r = cn;
        float zn2 = __shfl_down(zn, 1);
        if ((tid & 1) == 0){
          u32 pk = (u32)f2b(zn) | ((u32)f2b(zn2) << 16);
          *(u32*)(zallb + ((size_t)b*NOL + s)*1024 + d) = pk;
          coh_stu((u32*)(z1bf + prv*16384 + zswz(b, d)), pk);
        }
      }
      __syncthreads();   // gex reuse below
    }
    if (t < NOL){
      f32x4 acc = {0.f,0.f,0.f,0.f};
      const u16* Bd = wdecT + (size_t)(wg*16 + r)*1024 + q*8;
      #pragma unroll
      for (int i = 0; i < 4; ++i){
        int kt = wv*4 + i;
        acc = __builtin_amdgcn_mfma_f32_16x16x32_bf16(
                lds_frag(sZ0, r, kt*4+q), *(const bf16x8*)(Bd + kt*32), acc, 0,0,0);
      }
      #pragma unroll
      for (int rr = 0; rr < 4; ++rr) gex[wv][q*4+rr][r] = acc[rr];
      __syncthreads();
      if (tid < 256){
        int b = tid >> 4, j = tid & 15;
        float s2 = 0.f;
        #pragma unroll
        for (int w = 0; w < 8; ++w) s2 += gex[w][b][j];
        coh_stf(&dqf[b*1024 + wg*16 + j], tanhf(s2));
      }
    }
    bar_arrive(af, epoch);
    if (t == NOL){ bar_wait(af, epoch); break; }
    // prefetch phase-B pre rows (read-only) while other WGs arrive
    const int rbase = eb*512 + ch*128 + wv*16;
    u16x8 pp0[16], pp1[16];
    #pragma unroll
    for (int rr = 0; rr < 16; ++rr){
      const u16* pr = pre + (size_t)(rbase+rr)*1024 + lane*16;
      pp0[rr] = *(const u16x8*)(pr);
      pp1[rr] = *(const u16x8*)(pr+8);
    }
    bar_wait(af, epoch); epoch++;

    // ======== Phase B: escore = 2 * pre . dq (128 rows per WG) ========
    {
      { u64 v = coh_ld64((const char*)(dqf + eb*1024) + tid*8);
        *(u64*)((char*)sDq + tid*8) = v; }
      __syncthreads();
      float qv[16];
      #pragma unroll
      for (int i = 0; i < 4; ++i)
        *(float4*)(qv + i*4) = *(const float4*)(sDq + lane*16 + i*4);
      #pragma unroll
      for (int rr = 0; rr < 16; ++rr){
        float acc = 0.f;
        #pragma unroll
        for (int j = 0; j < 8; ++j){
          acc += b2f(pp0[rr][j])*qv[j];
          acc += b2f(pp1[rr][j])*qv[8+j];
        }
        #pragma unroll
        for (int off = 32; off > 0; off >>= 1) acc += __shfl_xor(acc, off, 64);
        if (lane == 0) coh_stf(&esc[rbase+rr], 2.0f*acc);
      }
    }
    bar_arrive(af, epoch);
    // prefetch phase-C hpadT (read-only): e = ch*256 + (tid&255), t-half th
    const int e = ch*256 + (tid & 255), th = tid >> 8;
    u16x8 hp[32];
    {
      const u16* hpp = hpadT + ((size_t)eb*1024 + e)*512 + th*256;
      #pragma unroll
      for (int i = 0; i < 32; ++i) hp[i] = *(const u16x8*)(hpp + i*8);
    }
    bar_wait(af, epoch); epoch++;

    // ======== Phase C: softmax + att_c (b=eb, e-chunk ch) ========
    {
      if (tid < 256){
        u64 v = coh_ld64((const char*)(esc + eb*512) + tid*8);
        *(u64*)((char*)sEsc + tid*8) = v;
      }
      __syncthreads();
      float ev = (tid < len) ? sEsc[tid] : -INFINITY;
      sred[tid] = ev;
      __syncthreads();
      #pragma unroll
      for (int s2 = 256; s2 > 0; s2 >>= 1){
        if (tid < s2) sred[tid] = fmaxf(sred[tid], sred[tid+s2]);
        __syncthreads();
      }
      float mx = sred[0];
      __syncthreads();
      float p = (tid < len) ? expf(ev - mx) : 0.0f;
      sred[tid] = p;
      __syncthreads();
      #pragma unroll
      for (int s2 = 256; s2 > 0; s2 >>= 1){
        if (tid < s2) sred[tid] += sred[tid+s2];
        __syncthreads();
      }
      float inv = 1.0f/sred[0];
      sw[tid] = p*inv;
      __syncthreads();
      float acc = 0.f;
      #pragma unroll
      for (int i = 0; i < 32; ++i){
        #pragma unroll
        for (int j = 0; j < 8; ++j) acc += sw[th*256 + i*8 + j]*b2f(hp[i][j]);
      }
      spart[th][tid & 255] = acc;
      __syncthreads();
      if (tid < 256){
        float s2 = spart[0][tid] + spart[1][tid];
        float s2n = __shfl_down(s2, 1);
        if ((tid & 1) == 0){
          int e2 = ch*256 + tid;
          u32 pk = (u32)f2b(s2) | ((u32)f2b(s2n) << 16);
          coh_stu((u32*)(attc + zswz(eb, e2)), pk);
        }
      }
    }
    bar_arrive(af, epoch);
    bar_wait(af, epoch); epoch++;

    // ======== Phase D: gemm0 + cell0(t) -> z0(t) ========
    {
      stage32((const char*)attc, (char*)sAt, tid);
      __syncthreads();
      f32x4 acc = {0.f,0.f,0.f,0.f};
      const u16* As = h ? sZ0 : sAt;
      const u16* Bs = (h ? wh0 : w0c) + (size_t)(g*1024 + wg*16 + r)*1024 + q*8;
      #pragma unroll 8
      for (int kt = 0; kt < 32; ++kt)
        acc = __builtin_amdgcn_mfma_f32_16x16x32_bf16(
                lds_frag(As, r, kt*4+q), *(const bf16x8*)(Bs + kt*32), acc, 0,0,0);
      #pragma unroll
      for (int rr = 0; rr < 4; ++rr) gex[wv][q*4+rr][r] = acc[rr];
      __syncthreads();
      if (tid < 256){
        int b = tid >> 4, dd = tid & 15, d = wg*16 + dd;
        const u16* gr = gey + ((size_t)b*NOL + t)*4096 + d;
        float g0 = gex[0][b][dd] + gex[1][b][dd] + b2f(gr[0]);
        float g1 = gex[2][b][dd] + gex[3][b][dd] + b2f(gr[1024]);
        float g2 = gex[4][b][dd] + gex[5][b][dd] + b2f(gr[2048]);
        float g3 = gex[6][b][dd] + gex[7][b][dd] + b2f(gr[3072]);
        float cn = sigf(g1)*c0r + sigf(g0)*tanhf(g2);
        float zn = sigf(g3)*tanhf(cn);
        c0r = cn;
        float zn2 = __shfl_down(zn, 1);
        if ((tid & 1) == 0){
          u32 pk = (u32)f2b(zn) | ((u32)f2b(zn2) << 16);
          coh_stu((u32*)(z0bf + cur*16384 + zswz(b, d)), pk);
        }
      }
    }
    bar_arrive(af, epoch);
    bar_wait(af, epoch); epoch++;
  }
}

// ---------------- per-row log_softmax + NLL + argmax (bf16 logits) ----------------
__global__ __launch_bounds__(256) void loss_kernel(
    const u16* __restrict__ logits, const int* __restrict__ ys, float* __restrict__ accum){
  int row = blockIdx.x;
  int tid = threadIdx.x;
  const u16* lr = logits + (size_t)row * NO;
  __shared__ float sv[256];
  __shared__ int   si[256];
  float mx = -INFINITY; int mi = 0;
  for (int n = tid; n < NO; n += 256){
    float v = b2f(lr[n]);
    if (v > mx){ mx = v; mi = n; }
  }
  sv[tid] = mx; si[tid] = mi;
  __syncthreads();
  for (int s=128; s>0; s>>=1){
    if (tid < s){
      if (sv[tid+s] > sv[tid] || (sv[tid+s]==sv[tid] && si[tid+s] < si[tid])){
        sv[tid] = sv[tid+s]; si[tid] = si[tid+s];
      }
    }
    __syncthreads();
  }
  float gmx = sv[0]; int gmi = si[0];
  __syncthreads();
  float ps = 0.0f;
  for (int n = tid; n < NO; n += 256) ps += expf(b2f(lr[n])-gmx);
  sv[tid] = ps;
  __syncthreads();
  for (int s=128; s>0; s>>=1){ if (tid<s) sv[tid] += sv[tid+s]; __syncthreads(); }
  if (tid==0){
    int b = row / NOL, l = row - b*NOL;
    int label = (l < NL) ? ys[b*NL + l] : TOK_EOS;
    float lse = gmx + logf(sv[0]);
    float nll = lse - b2f(lr[label]);
    atomicAdd(&accum[0], nll);
    atomicAdd(&accum[1], (gmi==label) ? 1.0f : 0.0f);
  }
}

__global__ void finalize_kernel(const float* __restrict__ accum, float* __restrict__ out){
  out[0] = accum[0] / (float)NROWS * (float)(NOL-1);
  out[1] = accum[1] / (float)NROWS;
}

extern "C" void kernel_launch(void* const* d_in, const int* in_sizes, int n_in,
                              void* d_out, int out_size, void* d_ws, size_t ws_size,
                              hipStream_t stream){
  const float* hpad  = (const float*)d_in[0];
  const int*   hlen  = (const int*)  d_in[1];
  const int*   ys    = (const int*)  d_in[2];
  const float* embed = (const float*)d_in[3];
  const float* Wenc  = (const float*)d_in[4];
  const float* Wdec  = (const float*)d_in[5];
  const float* Wih0  = (const float*)d_in[6];
  const float* Whh0  = (const float*)d_in[7];
  const float* bih0  = (const float*)d_in[8];
  const float* bhh0  = (const float*)d_in[9];
  const float* Wih1  = (const float*)d_in[10];
  const float* Whh1  = (const float*)d_in[11];
  const float* bih1  = (const float*)d_in[12];
  const float* bhh1  = (const float*)d_in[13];
  const float* Wout  = (const float*)d_in[14];
  const float* bout  = (const float*)d_in[15];
  float* out = (float*)d_out;

  char* ws = (char*)d_ws;
  size_t cur = 0;
  auto alloc = [&](size_t bytes) -> char* {
    char* p = ws + cur;
    cur += (bytes + 255) & ~(size_t)255;
    return p;
  };
  u16*   pre_bf   = (u16*)  alloc(16777216);   // [8192][1024]
  u16*   hpadT    = (u16*)  alloc(16777216);   // [16][1024][512]
  u16*   w0c      = (u16*)  alloc(8388608);    // Wih0[:,1024:]
  u16*   wh0      = (u16*)  alloc(8388608);
  u16*   w1c      = (u16*)  alloc(8388608);
  u16*   wh1      = (u16*)  alloc(8388608);
  u16*   wdecT    = (u16*)  alloc(2097152);    // [1024][1024]
  u16*   wencT    = (u16*)  alloc(2097152);    // [1024][1024]
  u16*   woutT    = (u16*)  alloc(20578304);   // [10048][1024]
  u16*   gey      = (u16*)  alloc(16908288);   // [2064][4096]
  u16*   zallb    = (u16*)  alloc(4325376);    // [2112][1024]
  u16*   logits   = (u16*)  alloc(41280000);   // [2064][10000]
  float* dqf      = (float*)alloc(65536);
  float* esc      = (float*)alloc(32768);
  u16*   attc     = (u16*)  alloc(32768);
  float* bias1    = (float*)alloc(16384);
  // ---- zeroed region (contiguous) ----
  u32*   af       = (u32*)  alloc(32768);      // 64 WGs x 512B flag lines
  u16*   z0bf     = (u16*)  alloc(65536);      // [2][16][1024]
  u16*   z1bf     = (u16*)  alloc(65536);
  float* accum    = (float*)alloc(128);
  // zero bytes = 32768 + 65536 + 65536 + 128 = 163968 -> 10248 uint4
  zero4_kernel<<<41, 256, 0, stream>>>((uint4*)af, 10248);

  tcvt_kernel<<<dim3(32,32),  256, 0, stream>>>(Wenc, 1024, 1024, wencT);
  tcvt_kernel<<<dim3(32,32),  256, 0, stream>>>(Wdec, 1024, 1024, wdecT);
  tcvt_kernel<<<dim3(313,32), 256, 0, stream>>>(Wout, 1024, NO,   woutT);
  cvt_nk_kernel<<<4096, 256, 0, stream>>>(Wih0, 2048, 1024, w0c);
  cvt_nk_kernel<<<4096, 256, 0, stream>>>(Whh0, 1024, 0, wh0);
  cvt_nk_kernel<<<4096, 256, 0, stream>>>(Wih1, 1024, 0, w1c);
  cvt_nk_kernel<<<4096, 256, 0, stream>>>(Whh1, 1024, 0, wh1);
  hpadT_kernel<<<dim3(32,16,16), 256, 0, stream>>>(hpad, hlen, hpadT);
  bias_add_kernel<<<16, 256, 0, stream>>>(bih1, bhh1, bias1);
  preenc_mfma<<<dim3(128,16), 256, 0, stream>>>(hpad, hlen, wencT, pre_bf);
  gey_mfma<<<dim3(33,64), 256, 0, stream>>>(ys, embed, Wih0, bih0, bhh0, gey);

  hipFuncSetAttribute((const void*)seq_kernel,
                      hipFuncAttributeMaxDynamicSharedMemorySize, 71680);
  seq_kernel<<<NBLK, 512, 71680, stream>>>(pre_bf, hpadT, w0c, wh0, w1c, wh1,
                                           wdecT, gey, bias1, hlen, dqf, esc, attc,
                                           z0bf, z1bf, zallb, af);

  logits_mfma<<<dim3(33,157), 256, 0, stream>>>(zallb, woutT, bout, logits);
  loss_kernel<<<NROWS, 256, 0, stream>>>(logits, ys, accum);
  finalize_kernel<<<1, 1, 0, stream>>>(accum, out);
}

// Round 11
// 4106.380 us; speedup vs baseline: 2.0106x; 1.6094x over previous
//
#include <hip/hip_runtime.h>
#include <math.h>

#define NB 16
#define NT 512
#define NE 1024
#define ND 1024
#define NA 1024
#define NO 10000
#define NL 128
#define NOL 129
#define NROWS (NB*NOL)   /* 2064 */
#define TOK_SOS 9999
#define TOK_EOS 9999
#define NBLK 256

typedef unsigned short u16;
typedef unsigned int u32;
typedef __bf16 bf16x8 __attribute__((ext_vector_type(8)));
typedef float f32x4 __attribute__((ext_vector_type(4)));
typedef unsigned short u16x8 __attribute__((ext_vector_type(8)));
typedef unsigned short u16x4 __attribute__((ext_vector_type(4)));

__device__ __forceinline__ float sigf(float x){ return 1.0f/(1.0f+expf(-x)); }
__device__ __forceinline__ float b2f(u16 s){
  union { u32 i; float f; } u; u.i = ((u32)s) << 16; return u.f;
}
__device__ __forceinline__ u16 f2b(float f){
  union { float f; u32 i; } u; u.f = f;
  u32 r = u.i + 0x7FFFu + ((u.i >> 16) & 1u);
  return (u16)(r >> 16);
}
__device__ __forceinline__ bf16x8 cvt8(float4 a, float4 b){
  union { u16 u[8]; bf16x8 v; } c;
  c.u[0]=f2b(a.x); c.u[1]=f2b(a.y); c.u[2]=f2b(a.z); c.u[3]=f2b(a.w);
  c.u[4]=f2b(b.x); c.u[5]=f2b(b.y); c.u[6]=f2b(b.z); c.u[7]=f2b(b.w);
  return c.v;
}
__device__ __forceinline__ bf16x8 zero8(){
  union { u16 u[8]; bf16x8 v; } c;
  #pragma unroll
  for (int i=0;i<8;++i) c.u[i]=0;
  return c.v;
}

// ---- producer write-through stores / barrier flag ops (agent-relaxed, proven r5/r9) ----
__device__ __forceinline__ void coh_stf(float* p, float v){
  __hip_atomic_store(p, v, __ATOMIC_RELAXED, __HIP_MEMORY_SCOPE_AGENT);
}
__device__ __forceinline__ u32 coh_ldu(const u32* p){
  return __hip_atomic_load((u32*)p, __ATOMIC_RELAXED, __HIP_MEMORY_SCOPE_AGENT);
}
__device__ __forceinline__ void coh_stu(u32* p, u32 v){
  __hip_atomic_store(p, v, __ATOMIC_RELAXED, __HIP_MEMORY_SCOPE_AGENT);
}
__device__ __forceinline__ float dot8(bf16x8 a, bf16x8 b){
  float s = 0.f;
  #pragma unroll
  for (int j=0;j<8;++j) s += (float)a[j]*(float)b[j];
  return s;
}

// ---------------- zero ----------------
__global__ void zero4_kernel(uint4* __restrict__ p, int n){
  int i = blockIdx.x*256 + threadIdx.x;
  if (i < n) p[i] = make_uint4(0,0,0,0);
}

// ---------------- f32 [4096][ld] (col slice) -> bf16 [4096][1024] ----------------
__global__ __launch_bounds__(256) void cvt_nk_kernel(
    const float* __restrict__ src, int ld, int off, u16* __restrict__ dst){
  int i = (blockIdx.x*256 + threadIdx.x)*4;
  int row = i >> 10, col = i & 1023;
  float4 v = *(const float4*)(src + (size_t)row*ld + off + col);
  u16x4 o = { f2b(v.x), f2b(v.y), f2b(v.z), f2b(v.w) };
  *(u16x4*)(dst + i) = o;
}

// ---------------- transpose-convert: src f32 [R][C] -> dst bf16 [C'][R] ----------------
__global__ __launch_bounds__(256) void tcvt_kernel(
    const float* __restrict__ src, int R, int C, u16* __restrict__ dst){
  __shared__ float tile[32][33];
  const int c0 = blockIdx.x*32, r0 = blockIdx.y*32;
  const int tx = threadIdx.x & 31, ty = threadIdx.x >> 5;
  #pragma unroll
  for (int k = 0; k < 4; ++k){
    int rr = ty + k*8;
    int c = c0 + tx;
    float v = (c < C) ? src[(size_t)(r0+rr)*C + c] : 0.0f;
    tile[rr][tx] = v;
  }
  __syncthreads();
  #pragma unroll
  for (int k = 0; k < 4; ++k){
    int cc = ty + k*8;
    dst[(size_t)(c0+cc)*R + r0 + tx] = f2b(tile[tx][cc]);
  }
}

// ---------------- hpad [16][512][1024] f32 -> masked bf16 transposed [16][1024][512] -------
__global__ __launch_bounds__(256) void hpadT_kernel(
    const float* __restrict__ hpad, const int* __restrict__ hlen, u16* __restrict__ dst){
  __shared__ float tile[32][33];
  const int e0 = blockIdx.x*32, t0 = blockIdx.y*32, b = blockIdx.z;
  const int tx = threadIdx.x & 31, ty = threadIdx.x >> 5;
  const int len = hlen[b];
  #pragma unroll
  for (int k = 0; k < 4; ++k){
    int r = ty + k*8;
    tile[r][tx] = hpad[((size_t)b*512 + t0 + r)*1024 + e0 + tx];
  }
  __syncthreads();
  #pragma unroll
  for (int k = 0; k < 4; ++k){
    int el = ty + k*8;
    float m = (t0 + tx < len) ? 1.0f : 0.0f;
    dst[((size_t)b*1024 + e0 + el)*512 + t0 + tx] = f2b(tile[tx][el]*m);
  }
}

// ---------------- bias1 = bih1 + bhh1 ----------------
__global__ void bias_add_kernel(const float* __restrict__ a, const float* __restrict__ b,
                                float* __restrict__ o){
  int i = blockIdx.x*256 + threadIdx.x;
  if (i < 4096) o[i] = a[i] + b[i];
}

// ---------------- pre_enc = tanh(mask(hpad) @ Wenc) via MFMA -> bf16 [8192][1024] ----------
__global__ __launch_bounds__(256) void preenc_mfma(
    const float* __restrict__ hpad, const int* __restrict__ hlen,
    const u16* __restrict__ wencT, u16* __restrict__ pre){
  const int m0 = blockIdx.x*64, n0 = blockIdx.y*64;
  const int tid = threadIdx.x, lane = tid & 63, wv = tid >> 6;
  const int r = lane & 15, q = lane >> 4;
  const int ar = m0 + wv*16 + r;
  const bool on = (ar & 511) < hlen[ar >> 9];
  const float* ap = hpad + (size_t)ar*1024 + q*8;
  f32x4 acc[4] = {{0,0,0,0},{0,0,0,0},{0,0,0,0},{0,0,0,0}};
  for (int kt = 0; kt < 32; ++kt){
    bf16x8 a;
    if (on){
      float4 v0 = *(const float4*)(ap + kt*32);
      float4 v1 = *(const float4*)(ap + kt*32 + 4);
      a = cvt8(v0, v1);
    } else a = zero8();
    #pragma unroll
    for (int s = 0; s < 4; ++s){
      const u16* bp = wencT + (size_t)(n0 + s*16 + r)*1024 + kt*32 + q*8;
      acc[s] = __builtin_amdgcn_mfma_f32_16x16x32_bf16(a, *(const bf16x8*)bp, acc[s], 0,0,0);
    }
  }
  #pragma unroll
  for (int s = 0; s < 4; ++s)
    #pragma unroll
    for (int rr = 0; rr < 4; ++rr){
      int row = m0 + wv*16 + q*4 + rr, col = n0 + s*16 + r;
      pre[(size_t)row*1024 + col] = f2b(tanhf(acc[s][rr]));
    }
}

// ---------------- gey = embed[ys_in] @ Wih0[:,0:1024]^T + bih0 + bhh0 via MFMA -> bf16 -----
__global__ __launch_bounds__(256) void gey_mfma(
    const int* __restrict__ ys, const float* __restrict__ embed,
    const float* __restrict__ Wih0, const float* __restrict__ bih0,
    const float* __restrict__ bhh0, u16* __restrict__ gey){
  const int m0 = blockIdx.x*64, n0 = blockIdx.y*64;
  const int tid = threadIdx.x, lane = tid & 63, wv = tid >> 6;
  const int r = lane & 15, q = lane >> 4;
  const int ar = m0 + wv*16 + r;
  int tok = 0;
  if (ar < NROWS){
    int bb = ar / NOL, l = ar - bb*NOL;
    tok = (l==0) ? TOK_SOS : ys[bb*NL + l - 1];
  }
  const float* ap = embed + (size_t)tok*1024 + q*8;
  f32x4 acc[4] = {{0,0,0,0},{0,0,0,0},{0,0,0,0},{0,0,0,0}};
  for (int kt = 0; kt < 32; ++kt){
    float4 v0 = *(const float4*)(ap + kt*32);
    float4 v1 = *(const float4*)(ap + kt*32 + 4);
    bf16x8 a = cvt8(v0, v1);
    #pragma unroll
    for (int s = 0; s < 4; ++s){
      const float* bp = Wih0 + (size_t)(n0 + s*16 + r)*2048 + kt*32 + q*8;
      float4 w0 = *(const float4*)(bp);
      float4 w1 = *(const float4*)(bp + 4);
      acc[s] = __builtin_amdgcn_mfma_f32_16x16x32_bf16(a, cvt8(w0,w1), acc[s], 0,0,0);
    }
  }
  #pragma unroll
  for (int s = 0; s < 4; ++s)
    #pragma unroll
    for (int rr = 0; rr < 4; ++rr){
      int row = m0 + wv*16 + q*4 + rr, col = n0 + s*16 + r;
      if (row < NROWS)
        gey[(size_t)row*4096 + col] = f2b(acc[s][rr] + bih0[col] + bhh0[col]);
    }
}

// ---------------- logits = zallb @ woutT^T + bout via MFMA -> bf16 [2064][10000] -----------
__global__ __launch_bounds__(256) void logits_mfma(
    const u16* __restrict__ zallb, const u16* __restrict__ woutT,
    const float* __restrict__ bout, u16* __restrict__ logits){
  const int m0 = blockIdx.x*64, n0 = blockIdx.y*64;
  const int tid = threadIdx.x, lane = tid & 63, wv = tid >> 6;
  const int r = lane & 15, q = lane >> 4;
  const int ar = m0 + wv*16 + r;
  const u16* ap = zallb + (size_t)ar*1024 + q*8;
  f32x4 acc[4] = {{0,0,0,0},{0,0,0,0},{0,0,0,0},{0,0,0,0}};
  for (int kt = 0; kt < 32; ++kt){
    bf16x8 a = *(const bf16x8*)(ap + kt*32);
    #pragma unroll
    for (int s = 0; s < 4; ++s){
      const u16* bp = woutT + (size_t)(n0 + s*16 + r)*1024 + kt*32 + q*8;
      acc[s] = __builtin_amdgcn_mfma_f32_16x16x32_bf16(a, *(const bf16x8*)bp, acc[s], 0,0,0);
    }
  }
  #pragma unroll
  for (int s = 0; s < 4; ++s)
    #pragma unroll
    for (int rr = 0; rr < 4; ++rr){
      int row = m0 + wv*16 + q*4 + rr, col = n0 + s*16 + r;
      if (row < NROWS && col < NO)
        logits[(size_t)row*NO + col] = f2b(acc[s][rr] + bout[col]);
    }
}

// ---------------- round-5 flag/broadcast grid barrier (1 poller/WG, no fences) -------------
__device__ __forceinline__ void gbar(u32* af, int epoch){
  __syncthreads();
  if (blockIdx.x == 0){
    int w = threadIdx.x;
    if (w > 0){
      while (coh_ldu(&af[w << 5]) < (u32)epoch) __builtin_amdgcn_s_sleep(1);
    }
    __syncthreads();
    if (threadIdx.x == 0) coh_stu(&af[0], (u32)epoch);
  } else {
    if (threadIdx.x == 0){
      coh_stu(&af[blockIdx.x << 5], (u32)epoch);
      while (coh_ldu(&af[0]) < (u32)epoch) __builtin_amdgcn_s_sleep(1);
    }
    __syncthreads();
  }
}

// one 16x16 output tile, K=512 slice per wave; weights from LDS, A cached from ring
__device__ __forceinline__ f32x4 tile_gemm(const u16* lw, const u16* ab){
  f32x4 acc = {0.f,0.f,0.f,0.f};
  #pragma unroll
  for (int kt = 0; kt < 16; ++kt){
    bf16x8 a = *(const bf16x8*)(ab + kt*32);
    bf16x8 b = *(const bf16x8*)(lw + kt*512);
    acc = __builtin_amdgcn_mfma_f32_16x16x32_bf16(a, b, acc, 0, 0, 0);
  }
  return acc;
}

// ---------------- persistent sequential kernel: rings + L2-broadcast reads ----------------
// 256 WGs x 256 threads; each WG owns 16 gate-rows (LDS-resident weights).
// All per-step state goes to write-once ring slots: producers write-through (agent),
// consumers use normal cached loads (first touch per XCD -> L3 refill -> L2 broadcast).
__global__ __launch_bounds__(256, 1) void seq_kernel(
    const u16* __restrict__ pre,    // [8192][1024] bf16 (cached, L2-resident slices)
    const u16* __restrict__ hpadT,  // [16][1024][512] bf16 masked (cached)
    const u16* __restrict__ w0c, const u16* __restrict__ wh0,
    const u16* __restrict__ w1c, const u16* __restrict__ wh1,
    const u16* __restrict__ wdecT,  // [1024 n][1024 k] bf16 (cached)
    const u16* __restrict__ gey,    // [2064][4096] bf16 (cached)
    const float* __restrict__ bias1,// [4096]
    const int* __restrict__ hlen,
    u16* dqr,                       // ring [129][16][1024] bf16
    float* escr,                    // ring [129][16][512] f32
    u16* attcr,                     // ring [129][16][1024] bf16
    u16* z0r,                       // ring [130][16][1024] bf16 (slot0 zeroed)
    u16* z1r,                       // ring [130][16][1024] bf16 (slot0 zeroed)
    u16* zallb,                     // [2112][1024] bf16 (normal stores)
    u32* af)
{
  // one-time invalidate: kill stale L1/L2 lines from the previous graph replay
  __builtin_amdgcn_fence(__ATOMIC_ACQUIRE, "agent");

  const int wg = blockIdx.x, tid = threadIdx.x;
  const int lane = tid & 63, wv = tid >> 6;
  const int r = lane & 15, q = lane >> 4;

  extern __shared__ __align__(16) u16 dynlds[];
  u16* lw1 = dynlds;            // [kb 0..255][c 0..15][8] = 64 KB (layer1 gates)
  u16* lw0 = dynlds + 32768;    // 64 KB (layer0 gates)
  __shared__ float sred[256];
  __shared__ float sw[512];
  __shared__ float spart[4][64];
  __shared__ float gex[4][16][16];
  __shared__ float sdq[16*16*4];

  const int dg16 = (wg & 63)*16, sub4 = (wg >> 6)*4;

  // ---- stage gate weights into LDS (once) ----
  #pragma unroll
  for (int it = 0; it < 16; ++it){
    int m = tid + it*256;          // m = kb*16 + c
    int kb = m >> 4, c = m & 15;
    int k0 = kb*8;
    int gi = c >> 2;
    int d  = dg16 + sub4 + (c & 3);
    size_t gr = (size_t)(gi*1024 + d)*1024;
    const u16* s1 = (k0 < 1024) ? (w1c + gr + k0) : (wh1 + gr + k0 - 1024);
    const u16* s0 = (k0 < 1024) ? (w0c + gr + k0) : (wh0 + gr + k0 - 1024);
    *(u16x8*)(lw1 + (m << 3)) = *(const u16x8*)s1;
    *(u16x8*)(lw0 + (m << 3)) = *(const u16x8*)s0;
  }
  __syncthreads();

  float c0r = 0.f, c1r = 0.f;    // cell state for (b=tid>>2, d=dg16+sub4+(tid&3)), tid<64
  int epoch = 1;
  const int lwoff = ((wv*64 + q)*16 + r) << 3;

  for (int t = 0; t <= NOL; ++t){
    const u16* z0t = z0r + (size_t)t*16384;        // z0 state entering step t
    u16* dq_t   = dqr   + (size_t)t*16384;
    float* esc_t= escr  + (size_t)t*8192;
    u16* attc_t = attcr + (size_t)t*16384;

    // ======== Phase A: gemm1+cell1(t-1), dq(t) ========
    if (t >= 1){
      const int s = t - 1;
      const u16* z1p = z1r + (size_t)(t-1)*16384;  // z1 state entering step s
      const u16* ab = ((wv < 2) ? z0t : z1p) + r*1024 + (wv & 1)*512 + q*8;
      f32x4 acc = tile_gemm(lw1 + lwoff, ab);
      #pragma unroll
      for (int rr = 0; rr < 4; ++rr) gex[wv][q*4+rr][r] = acc[rr];
      __syncthreads();
      if (tid < 64){
        int b = tid >> 2, dd = tid & 3, d = dg16 + sub4 + dd;
        float g0 = gex[0][b][0*4+dd] + gex[1][b][0*4+dd] + gex[2][b][0*4+dd] + gex[3][b][0*4+dd];
        float g1 = gex[0][b][1*4+dd] + gex[1][b][1*4+dd] + gex[2][b][1*4+dd] + gex[3][b][1*4+dd];
        float g2 = gex[0][b][2*4+dd] + gex[1][b][2*4+dd] + gex[2][b][2*4+dd] + gex[3][b][2*4+dd];
        float g3 = gex[0][b][3*4+dd] + gex[1][b][3*4+dd] + gex[2][b][3*4+dd] + gex[3][b][3*4+dd];
        g0 += bias1[d]; g1 += bias1[1024+d]; g2 += bias1[2048+d]; g3 += bias1[3072+d];
        float cn = sigf(g1)*c1r + sigf(g0)*tanhf(g2);
        float zn = sigf(g3)*tanhf(cn);
        c1r = cn;
        float zn2 = __shfl_down(zn, 1);
        if ((tid & 1) == 0){
          u32 pk = (u32)f2b(zn) | ((u32)f2b(zn2) << 16);
          *(u32*)(zallb + ((size_t)b*NOL + s)*1024 + d) = pk;           // normal store
          coh_stu((u32*)(z1r + (size_t)t*16384 + b*1024 + d), pk);      // ring write-through
        }
      }
      __syncthreads();   // gex reuse below
    }
    if (t < NOL){
      // dq: this WG computes n = wg*4 .. wg*4+3 for all 16 batches (cached z0 reads)
      const int b = tid & 15, ks = tid >> 4;
      float a4[4] = {0.f,0.f,0.f,0.f};
      #pragma unroll
      for (int i = 0; i < 8; ++i){
        bf16x8 za = *(const bf16x8*)(z0t + b*1024 + ks*64 + i*8);
        #pragma unroll
        for (int nn = 0; nn < 4; ++nn){
          bf16x8 wb = *(const bf16x8*)(wdecT + (size_t)(wg*4+nn)*1024 + ks*64 + i*8);
          a4[nn] += dot8(za, wb);
        }
      }
      #pragma unroll
      for (int nn = 0; nn < 4; ++nn) sdq[(ks*16 + b)*4 + nn] = a4[nn];
      __syncthreads();
      if (tid < 64){
        int b2 = tid >> 2, nn = tid & 3;
        float s2 = 0.f;
        #pragma unroll
        for (int ks2 = 0; ks2 < 16; ++ks2) s2 += sdq[(ks2*16 + b2)*4 + nn];
        float dv = tanhf(s2);
        float dv2 = __shfl_down(dv, 1);
        if ((tid & 1) == 0){
          u32 pk = (u32)f2b(dv) | ((u32)f2b(dv2) << 16);
          coh_stu((u32*)(dq_t + b2*1024 + wg*4 + nn), pk);
        }
      }
    }
    gbar(af, epoch++);
    if (t == NOL) break;

    // ======== Phase B: escore = 2 * pre . dq  (32 rows per WG; cached dq reads) ========
    {
      const int rbase = wg*32 + wv*8;
      const int b = (wg*32) >> 9;
      const u16* dqb = dq_t + b*1024 + lane*16;
      u16x8 d0 = *(const u16x8*)(dqb);
      u16x8 d1 = *(const u16x8*)(dqb + 8);
      float qv[16];
      #pragma unroll
      for (int j = 0; j < 8; ++j){ qv[j] = b2f(d0[j]); qv[8+j] = b2f(d1[j]); }
      #pragma unroll
      for (int rr = 0; rr < 8; ++rr){
        const u16* pr = pre + (size_t)(rbase+rr)*1024 + lane*16;
        u16x8 p0 = *(const u16x8*)(pr);
        u16x8 p1 = *(const u16x8*)(pr+8);
        float acc = 0.f;
        #pragma unroll
        for (int j = 0; j < 8; ++j){
          acc += b2f(p0[j])*qv[j];
          acc += b2f(p1[j])*qv[8+j];
        }
        #pragma unroll
        for (int off = 32; off > 0; off >>= 1) acc += __shfl_xor(acc, off, 64);
        if (lane == 0) coh_stf(&esc_t[rbase+rr], 2.0f*acc);
      }
    }
    gbar(af, epoch++);

    // ======== Phase C: softmax + att_c (b = wg>>4, 64-col e-slice; cached esc reads) ======
    {
      const int b = wg >> 4, ec = wg & 15;
      const int len = hlen[b];
      float e0 = (tid < len)     ? esc_t[b*512 + tid]       : -INFINITY;
      float e1 = (tid+256 < len) ? esc_t[b*512 + tid + 256] : -INFINITY;
      sred[tid] = fmaxf(e0, e1);
      __syncthreads();
      #pragma unroll
      for (int s2 = 128; s2 > 0; s2 >>= 1){
        if (tid < s2) sred[tid] = fmaxf(sred[tid], sred[tid+s2]);
        __syncthreads();
      }
      float mx = sred[0];
      __syncthreads();
      float p0 = (tid < len)     ? expf(e0 - mx) : 0.0f;
      float p1 = (tid+256 < len) ? expf(e1 - mx) : 0.0f;
      sred[tid] = p0 + p1;
      __syncthreads();
      #pragma unroll
      for (int s2 = 128; s2 > 0; s2 >>= 1){
        if (tid < s2) sred[tid] += sred[tid+s2];
        __syncthreads();
      }
      float inv = 1.0f/sred[0];
      sw[tid] = p0*inv; sw[tid+256] = p1*inv;
      __syncthreads();
      const int el = tid & 63, th = tid >> 6;
      const u16* hp = hpadT + ((size_t)b*1024 + ec*64 + el)*512 + th*128;
      float acc = 0.f;
      #pragma unroll
      for (int i = 0; i < 16; ++i){
        u16x8 v = *(const u16x8*)(hp + i*8);
        #pragma unroll
        for (int j = 0; j < 8; ++j) acc += sw[th*128 + i*8 + j]*b2f(v[j]);
      }
      spart[th][el] = acc;
      __syncthreads();
      if (tid < 64){
        float s2 = spart[0][tid]+spart[1][tid]+spart[2][tid]+spart[3][tid];
        float s2n = __shfl_down(s2, 1);
        if ((tid & 1) == 0){
          u32 pk = (u32)f2b(s2) | ((u32)f2b(s2n) << 16);
          coh_stu((u32*)(attc_t + b*1024 + ec*64 + tid), pk);
        }
      }
    }
    gbar(af, epoch++);

    // ======== Phase D: gemm0 + cell0(t) -> z0 ring slot t+1 ========
    {
      const u16* ab = ((wv < 2) ? attc_t : z0t) + r*1024 + (wv & 1)*512 + q*8;
      f32x4 acc = tile_gemm(lw0 + lwoff, ab);
      #pragma unroll
      for (int rr = 0; rr < 4; ++rr) gex[wv][q*4+rr][r] = acc[rr];
      __syncthreads();
      if (tid < 64){
        int b = tid >> 2, dd = tid & 3, d = dg16 + sub4 + dd;
        const u16* gr = gey + ((size_t)b*NOL + t)*4096 + d;
        float g0 = gex[0][b][0*4+dd] + gex[1][b][0*4+dd] + gex[2][b][0*4+dd] + gex[3][b][0*4+dd];
        float g1 = gex[0][b][1*4+dd] + gex[1][b][1*4+dd] + gex[2][b][1*4+dd] + gex[3][b][1*4+dd];
        float g2 = gex[0][b][2*4+dd] + gex[1][b][2*4+dd] + gex[2][b][2*4+dd] + gex[3][b][2*4+dd];
        float g3 = gex[0][b][3*4+dd] + gex[1][b][3*4+dd] + gex[2][b][3*4+dd] + gex[3][b][3*4+dd];
        g0 += b2f(gr[0]); g1 += b2f(gr[1024]); g2 += b2f(gr[2048]); g3 += b2f(gr[3072]);
        float cn = sigf(g1)*c0r + sigf(g0)*tanhf(g2);
        float zn = sigf(g3)*tanhf(cn);
        c0r = cn;
        float zn2 = __shfl_down(zn, 1);
        if ((tid & 1) == 0){
          u32 pk = (u32)f2b(zn) | ((u32)f2b(zn2) << 16);
          coh_stu((u32*)(z0r + (size_t)(t+1)*16384 + b*1024 + d), pk);
        }
      }
    }
    gbar(af, epoch++);
  }
}

// ---------------- per-row log_softmax + NLL + argmax (bf16 logits) ----------------
__global__ __launch_bounds__(256) void loss_kernel(
    const u16* __restrict__ logits, const int* __restrict__ ys, float* __restrict__ accum){
  int row = blockIdx.x;
  int tid = threadIdx.x;
  const u16* lr = logits + (size_t)row * NO;
  __shared__ float sv[256];
  __shared__ int   si[256];
  float mx = -INFINITY; int mi = 0;
  for (int n = tid; n < NO; n += 256){
    float v = b2f(lr[n]);
    if (v > mx){ mx = v; mi = n; }
  }
  sv[tid] = mx; si[tid] = mi;
  __syncthreads();
  for (int s=128; s>0; s>>=1){
    if (tid < s){
      if (sv[tid+s] > sv[tid] || (sv[tid+s]==sv[tid] && si[tid+s] < si[tid])){
        sv[tid] = sv[tid+s]; si[tid] = si[tid+s];
      }
    }
    __syncthreads();
  }
  float gmx = sv[0]; int gmi = si[0];
  __syncthreads();
  float ps = 0.0f;
  for (int n = tid; n < NO; n += 256) ps += expf(b2f(lr[n])-gmx);
  sv[tid] = ps;
  __syncthreads();
  for (int s=128; s>0; s>>=1){ if (tid<s) sv[tid] += sv[tid+s]; __syncthreads(); }
  if (tid==0){
    int b = row / NOL, l = row - b*NOL;
    int label = (l < NL) ? ys[b*NL + l] : TOK_EOS;
    float lse = gmx + logf(sv[0]);
    float nll = lse - b2f(lr[label]);
    atomicAdd(&accum[0], nll);
    atomicAdd(&accum[1], (gmi==label) ? 1.0f : 0.0f);
  }
}

__global__ void finalize_kernel(const float* __restrict__ accum, float* __restrict__ out){
  out[0] = accum[0] / (float)NROWS * (float)(NOL-1);
  out[1] = accum[1] / (float)NROWS;
}

extern "C" void kernel_launch(void* const* d_in, const int* in_sizes, int n_in,
                              void* d_out, int out_size, void* d_ws, size_t ws_size,
                              hipStream_t stream){
  const float* hpad  = (const float*)d_in[0];
  const int*   hlen  = (const int*)  d_in[1];
  const int*   ys    = (const int*)  d_in[2];
  const float* embed = (const float*)d_in[3];
  const float* Wenc  = (const float*)d_in[4];
  const float* Wdec  = (const float*)d_in[5];
  const float* Wih0  = (const float*)d_in[6];
  const float* Whh0  = (const float*)d_in[7];
  const float* bih0  = (const float*)d_in[8];
  const float* bhh0  = (const float*)d_in[9];
  const float* Wih1  = (const float*)d_in[10];
  const float* Whh1  = (const float*)d_in[11];
  const float* bih1  = (const float*)d_in[12];
  const float* bhh1  = (const float*)d_in[13];
  const float* Wout  = (const float*)d_in[14];
  const float* bout  = (const float*)d_in[15];
  float* out = (float*)d_out;

  char* ws = (char*)d_ws;
  size_t cur = 0;
  auto alloc = [&](size_t bytes) -> char* {
    char* p = ws + cur;
    cur += (bytes + 255) & ~(size_t)255;
    return p;
  };
  u16*   pre_bf   = (u16*)  alloc(16777216);   // [8192][1024]
  u16*   hpadT    = (u16*)  alloc(16777216);   // [16][1024][512]
  u16*   w0c      = (u16*)  alloc(8388608);    // Wih0[:,1024:]
  u16*   wh0      = (u16*)  alloc(8388608);
  u16*   w1c      = (u16*)  alloc(8388608);
  u16*   wh1      = (u16*)  alloc(8388608);
  u16*   wdecT    = (u16*)  alloc(2097152);    // [1024][1024]
  u16*   wencT    = (u16*)  alloc(2097152);    // [1024][1024]
  u16*   woutT    = (u16*)  alloc(20578304);   // [10048][1024]
  u16*   gey      = (u16*)  alloc(16908288);   // [2064][4096]
  u16*   zallb    = (u16*)  alloc(4325376);    // [2112][1024]
  u16*   logits   = (u16*)  alloc(41280000);   // [2064][10000]
  float* bias1    = (float*)alloc(16384);
  // ---- write-once rings ----
  u16*   dqr      = (u16*)  alloc(129u*32768); // [129][16][1024] bf16
  float* escr     = (float*)alloc(129u*32768); // [129][16][512] f32
  u16*   attcr    = (u16*)  alloc(129u*32768); // [129][16][1024] bf16
  u16*   z0r      = (u16*)  alloc(130u*32768); // [130][16][1024] bf16
  u16*   z1r      = (u16*)  alloc(130u*32768); // [130][16][1024] bf16
  // ---- zeroed each launch ----
  u32*   af       = (u32*)  alloc(32768);      // barrier flags (af[0] = go word)
  float* accum    = (float*)alloc(128);

  // zero: af+accum (32768+128 = 32896 B -> 2056 uint4), z0r slot0, z1r slot0
  zero4_kernel<<<9, 256, 0, stream>>>((uint4*)af, 2056);
  zero4_kernel<<<8, 256, 0, stream>>>((uint4*)z0r, 2048);
  zero4_kernel<<<8, 256, 0, stream>>>((uint4*)z1r, 2048);

  tcvt_kernel<<<dim3(32,32),  256, 0, stream>>>(Wenc, 1024, 1024, wencT);
  tcvt_kernel<<<dim3(32,32),  256, 0, stream>>>(Wdec, 1024, 1024, wdecT);
  tcvt_kernel<<<dim3(313,32), 256, 0, stream>>>(Wout, 1024, NO,   woutT);
  cvt_nk_kernel<<<4096, 256, 0, stream>>>(Wih0, 2048, 1024, w0c);
  cvt_nk_kernel<<<4096, 256, 0, stream>>>(Whh0, 1024, 0, wh0);
  cvt_nk_kernel<<<4096, 256, 0, stream>>>(Wih1, 1024, 0, w1c);
  cvt_nk_kernel<<<4096, 256, 0, stream>>>(Whh1, 1024, 0, wh1);
  hpadT_kernel<<<dim3(32,16,16), 256, 0, stream>>>(hpad, hlen, hpadT);
  bias_add_kernel<<<16, 256, 0, stream>>>(bih1, bhh1, bias1);
  preenc_mfma<<<dim3(128,16), 256, 0, stream>>>(hpad, hlen, wencT, pre_bf);
  gey_mfma<<<dim3(33,64), 256, 0, stream>>>(ys, embed, Wih0, bih0, bhh0, gey);

  hipFuncSetAttribute((const void*)seq_kernel,
                      hipFuncAttributeMaxDynamicSharedMemorySize, 131072);
  seq_kernel<<<NBLK, 256, 131072, stream>>>(pre_bf, hpadT, w0c, wh0, w1c, wh1,
                                            wdecT, gey, bias1, hlen,
                                            dqr, escr, attcr, z0r, z1r, zallb, af);

  logits_mfma<<<dim3(33,157), 256, 0, stream>>>(zallb, woutT, bout, logits);
  loss_kernel<<<NROWS, 256, 0, stream>>>(logits, ys, accum);
  finalize_kernel<<<1, 1, 0, stream>>>(accum, out);
}

// Round 12
// 3565.252 us; speedup vs baseline: 2.3158x; 1.1518x over previous
//
#include <hip/hip_runtime.h>
#include <math.h>

#define NB 16
#define NT 512
#define NE 1024
#define ND 1024
#define NA 1024
#define NO 10000
#define NL 128
#define NOL 129
#define NROWS (NB*NOL)   /* 2064 */
#define TOK_SOS 9999
#define TOK_EOS 9999
#define NBLK 256

typedef unsigned short u16;
typedef unsigned int u32;
typedef __bf16 bf16x8 __attribute__((ext_vector_type(8)));
typedef float f32x4 __attribute__((ext_vector_type(4)));
typedef unsigned short u16x8 __attribute__((ext_vector_type(8)));
typedef unsigned short u16x4 __attribute__((ext_vector_type(4)));

__device__ __forceinline__ float sigf(float x){ return 1.0f/(1.0f+expf(-x)); }
__device__ __forceinline__ float b2f(u16 s){
  union { u32 i; float f; } u; u.i = ((u32)s) << 16; return u.f;
}
__device__ __forceinline__ u16 f2b(float f){
  union { float f; u32 i; } u; u.f = f;
  u32 r = u.i + 0x7FFFu + ((u.i >> 16) & 1u);
  return (u16)(r >> 16);
}
__device__ __forceinline__ float dot8(bf16x8 a, bf16x8 b){
  float s = 0.f;
  #pragma unroll
  for (int j=0;j<8;++j) s += (float)a[j]*(float)b[j];
  return s;
}

// ---- producer write-through stores / barrier flag ops (agent-relaxed, proven) ----
__device__ __forceinline__ void coh_stf(float* p, float v){
  __hip_atomic_store(p, v, __ATOMIC_RELAXED, __HIP_MEMORY_SCOPE_AGENT);
}
__device__ __forceinline__ u32 coh_ldu(const u32* p){
  return __hip_atomic_load((u32*)p, __ATOMIC_RELAXED, __HIP_MEMORY_SCOPE_AGENT);
}
__device__ __forceinline__ void coh_stu(u32* p, u32 v){
  __hip_atomic_store(p, v, __ATOMIC_RELAXED, __HIP_MEMORY_SCOPE_AGENT);
}

// ---------------- zero ----------------
__global__ void zero4_kernel(uint4* __restrict__ p, int n){
  int i = blockIdx.x*256 + threadIdx.x;
  if (i < n) p[i] = make_uint4(0,0,0,0);
}

// ---------------- f32 [4096][ld] (col slice) -> bf16 [4096][1024] ----------------
__global__ __launch_bounds__(256) void cvt_nk_kernel(
    const float* __restrict__ src, int ld, int off, u16* __restrict__ dst){
  int i = (blockIdx.x*256 + threadIdx.x)*4;
  int row = i >> 10, col = i & 1023;
  float4 v = *(const float4*)(src + (size_t)row*ld + off + col);
  u16x4 o = { f2b(v.x), f2b(v.y), f2b(v.z), f2b(v.w) };
  *(u16x4*)(dst + i) = o;
}

// ---------------- transpose-convert: src f32 [R][C] -> dst bf16 [C'][R] ----------------
__global__ __launch_bounds__(256) void tcvt_kernel(
    const float* __restrict__ src, int R, int C, u16* __restrict__ dst){
  __shared__ float tile[32][33];
  const int c0 = blockIdx.x*32, r0 = blockIdx.y*32;
  const int tx = threadIdx.x & 31, ty = threadIdx.x >> 5;
  #pragma unroll
  for (int k = 0; k < 4; ++k){
    int rr = ty + k*8;
    int c = c0 + tx;
    float v = (c < C) ? src[(size_t)(r0+rr)*C + c] : 0.0f;
    tile[rr][tx] = v;
  }
  __syncthreads();
  #pragma unroll
  for (int k = 0; k < 4; ++k){
    int cc = ty + k*8;
    dst[(size_t)(c0+cc)*R + r0 + tx] = f2b(tile[tx][cc]);
  }
}

// ---------------- hpad masked f32 -> bf16 [16][512][1024] ----------------
__global__ __launch_bounds__(256) void hpadbf_kernel(
    const float* __restrict__ hpad, const int* __restrict__ hlen, u16* __restrict__ dst){
  int i = (blockIdx.x*256 + threadIdx.x)*4;
  int bt = i >> 10;
  int b = bt >> 9, tt = bt & 511;
  float4 v = *(const float4*)(hpad + (size_t)i);
  float m = (tt < hlen[b]) ? 1.0f : 0.0f;
  u16x4 o = { f2b(v.x*m), f2b(v.y*m), f2b(v.z*m), f2b(v.w*m) };
  *(u16x4*)(dst + i) = o;
}

// ---------------- hpad [16][512][1024] f32 -> masked bf16 transposed [16][1024][512] -------
__global__ __launch_bounds__(256) void hpadT_kernel(
    const float* __restrict__ hpad, const int* __restrict__ hlen, u16* __restrict__ dst){
  __shared__ float tile[32][33];
  const int e0 = blockIdx.x*32, t0 = blockIdx.y*32, b = blockIdx.z;
  const int tx = threadIdx.x & 31, ty = threadIdx.x >> 5;
  const int len = hlen[b];
  #pragma unroll
  for (int k = 0; k < 4; ++k){
    int r = ty + k*8;
    tile[r][tx] = hpad[((size_t)b*512 + t0 + r)*1024 + e0 + tx];
  }
  __syncthreads();
  #pragma unroll
  for (int k = 0; k < 4; ++k){
    int el = ty + k*8;
    float m = (t0 + tx < len) ? 1.0f : 0.0f;
    dst[((size_t)b*1024 + e0 + el)*512 + t0 + tx] = f2b(tile[tx][el]*m);
  }
}

// ---------------- bias1 = bih1 + bhh1 ----------------
__global__ void bias_add_kernel(const float* __restrict__ a, const float* __restrict__ b,
                                float* __restrict__ o){
  int i = blockIdx.x*256 + threadIdx.x;
  if (i < 4096) o[i] = a[i] + b[i];
}

// ---------------- eys = bf16(embed[ys_in]) [2176][1024] (rows >= 2064 zeroed) --------------
__global__ __launch_bounds__(256) void eys_kernel(
    const int* __restrict__ ys, const float* __restrict__ embed, u16* __restrict__ eys){
  int row = blockIdx.x;
  int c = threadIdx.x*4;
  if (row < NROWS){
    int b = row / NOL, l = row - b*NOL;
    int tok = (l==0) ? TOK_SOS : ys[b*NL + l - 1];
    float4 v = *(const float4*)(embed + (size_t)tok*1024 + c);
    u16x4 o = { f2b(v.x), f2b(v.y), f2b(v.z), f2b(v.w) };
    *(u16x4*)(eys + (size_t)row*1024 + c) = o;
  } else {
    u16x4 o = {0,0,0,0};
    *(u16x4*)(eys + (size_t)row*1024 + c) = o;
  }
}

// ---------------- generic 128x128 bf16 MFMA tile body ----------------
// A [.][1024] bf16 row-major, B [.][1024] bf16 row-major (B row = output col).
// acc[a][s] covers rows m0+wv*32+a*16+{q*4+rr}, cols n0+s*16+r.
#define GEMM128_BODY(Aptr, Bptr) \
  const int tid = threadIdx.x, lane = tid & 63, wv = tid >> 6; \
  const int r = lane & 15, q = lane >> 4; \
  const int m0 = blockIdx.x*128, n0 = blockIdx.y*128; \
  const int ar0 = m0 + wv*32 + r; \
  f32x4 acc[2][8]; \
  _Pragma("unroll") \
  for (int a = 0; a < 2; ++a) \
    _Pragma("unroll") \
    for (int s = 0; s < 8; ++s) acc[a][s] = (f32x4){0.f,0.f,0.f,0.f}; \
  const u16* a0p = (Aptr) + (size_t)ar0*1024 + q*8; \
  const u16* a1p = a0p + 16*1024; \
  const u16* bp  = (Bptr) + (size_t)(n0 + r)*1024 + q*8; \
  for (int kt = 0; kt < 32; ++kt){ \
    bf16x8 av0 = *(const bf16x8*)(a0p + kt*32); \
    bf16x8 av1 = *(const bf16x8*)(a1p + kt*32); \
    _Pragma("unroll") \
    for (int s = 0; s < 8; ++s){ \
      bf16x8 bv = *(const bf16x8*)(bp + (size_t)s*16384 + kt*32); \
      acc[0][s] = __builtin_amdgcn_mfma_f32_16x16x32_bf16(av0, bv, acc[0][s], 0,0,0); \
      acc[1][s] = __builtin_amdgcn_mfma_f32_16x16x32_bf16(av1, bv, acc[1][s], 0,0,0); \
    } \
  }

// preenc: A = hpad_bf (masked), epilogue tanh -> pre [8192][1024]
__global__ __launch_bounds__(256) void preenc_g(
    const u16* __restrict__ hpadbf, const u16* __restrict__ wencT, u16* __restrict__ pre){
  GEMM128_BODY(hpadbf, wencT)
  #pragma unroll
  for (int a = 0; a < 2; ++a)
    #pragma unroll
    for (int s = 0; s < 8; ++s)
      #pragma unroll
      for (int rr = 0; rr < 4; ++rr){
        int row = m0 + wv*32 + a*16 + q*4 + rr, col = n0 + s*16 + r;
        pre[(size_t)row*1024 + col] = f2b(tanhf(acc[a][s][rr]));
      }
}

// gey: A = eys, B = w0e, epilogue + bih0 + bhh0 -> gey [2064][4096]
__global__ __launch_bounds__(256) void gey_g(
    const u16* __restrict__ eys, const u16* __restrict__ w0e,
    const float* __restrict__ bih0, const float* __restrict__ bhh0, u16* __restrict__ gey){
  GEMM128_BODY(eys, w0e)
  #pragma unroll
  for (int a = 0; a < 2; ++a)
    #pragma unroll
    for (int s = 0; s < 8; ++s)
      #pragma unroll
      for (int rr = 0; rr < 4; ++rr){
        int row = m0 + wv*32 + a*16 + q*4 + rr, col = n0 + s*16 + r;
        if (row < NROWS)
          gey[(size_t)row*4096 + col] = f2b(acc[a][s][rr] + bih0[col] + bhh0[col]);
      }
}

// logits: A = zallb, B = woutT, epilogue + bout -> logits [2064][10000]
__global__ __launch_bounds__(256) void logits_g(
    const u16* __restrict__ zallb, const u16* __restrict__ woutT,
    const float* __restrict__ bout, u16* __restrict__ logits){
  GEMM128_BODY(zallb, woutT)
  #pragma unroll
  for (int a = 0; a < 2; ++a)
    #pragma unroll
    for (int s = 0; s < 8; ++s)
      #pragma unroll
      for (int rr = 0; rr < 4; ++rr){
        int row = m0 + wv*32 + a*16 + q*4 + rr, col = n0 + s*16 + r;
        if (row < NROWS && col < NO)
          logits[(size_t)row*NO + col] = f2b(acc[a][s][rr] + bout[col]);
      }
}

// ---------------- grid barrier (round-5 flag/broadcast; 1 poller/WG) ----------------
__device__ __forceinline__ void gbar(u32* af, int epoch){
  __syncthreads();
  if (blockIdx.x == 0){
    int w = threadIdx.x;
    if (w > 0){
      while (coh_ldu(&af[w << 5]) < (u32)epoch) __builtin_amdgcn_s_sleep(1);
    }
    __syncthreads();
    if (threadIdx.x == 0) coh_stu(&af[0], (u32)epoch);
  } else {
    if (threadIdx.x == 0){
      coh_stu(&af[blockIdx.x << 5], (u32)epoch);
      while (coh_ldu(&af[0]) < (u32)epoch) __builtin_amdgcn_s_sleep(1);
    }
    __syncthreads();
  }
}

// ---------------- 16-WG group barrier (one hop: store + 16 parallel polls) ----------------
__device__ __forceinline__ void group_bar(u32* gfl, int epoch){
  __syncthreads();
  if (threadIdx.x == 0) coh_stu(&gfl[blockIdx.x << 5], (u32)epoch);
  const int base = blockIdx.x & ~15;
  if ((int)threadIdx.x < 16){
    while ((int)coh_ldu(&gfl[(base + threadIdx.x) << 5]) < epoch) __builtin_amdgcn_s_sleep(1);
  }
  __syncthreads();
}

// one 16x16 output tile, K=512 slice per wave; weights from LDS, A cached from ring
__device__ __forceinline__ f32x4 tile_gemm(const u16* lw, const u16* ab){
  f32x4 acc = {0.f,0.f,0.f,0.f};
  #pragma unroll
  for (int kt = 0; kt < 16; ++kt){
    bf16x8 a = *(const bf16x8*)(ab + kt*32);
    bf16x8 b = *(const bf16x8*)(lw + kt*512);
    acc = __builtin_amdgcn_mfma_f32_16x16x32_bf16(a, b, acc, 0, 0, 0);
  }
  return acc;
}

// ---------------- persistent sequential kernel: rings + L2-broadcast reads ----------------
__global__ __launch_bounds__(256, 1) void seq_kernel(
    const u16* __restrict__ pre,    // [8192][1024] bf16 (cached)
    const u16* __restrict__ hpadT,  // [16][1024][512] bf16 masked (cached)
    const u16* __restrict__ w0c, const u16* __restrict__ wh0,
    const u16* __restrict__ w1c, const u16* __restrict__ wh1,
    const u16* __restrict__ wdecT,  // [1024 n][1024 k] bf16 (cached)
    const u16* __restrict__ gey,    // [2064][4096] bf16 (cached)
    const float* __restrict__ bias1,// [4096]
    const int* __restrict__ hlen,
    u16* dqr,                       // ring [129][16][1024] bf16
    float* escr,                    // ring [129][16][512] f32
    u16* attcr,                     // ring [129][16][1024] bf16
    u16* z0r,                       // ring [130][16][1024] bf16 (slot0 zeroed)
    u16* z1r,                       // ring [130][16][1024] bf16 (slot0 zeroed)
    u16* zallb,                     // [2176][1024] bf16 (normal stores)
    u32* af, u32* gfl)
{
  __builtin_amdgcn_fence(__ATOMIC_ACQUIRE, "agent");

  const int wg = blockIdx.x, tid = threadIdx.x;
  const int lane = tid & 63, wv = tid >> 6;
  const int r = lane & 15, q = lane >> 4;

  extern __shared__ __align__(16) u16 dynlds[];
  u16* lw1 = dynlds;            // 64 KB (layer1 gates)
  u16* lw0 = dynlds + 32768;    // 64 KB (layer0 gates)
  __shared__ float sred[256];
  __shared__ float sw[512];
  __shared__ float spart[4][64];
  __shared__ float gex[4][16][16];
  __shared__ float sdq[16*16*4];

  const int dg16 = (wg & 63)*16, sub4 = (wg >> 6)*4;

  #pragma unroll
  for (int it = 0; it < 16; ++it){
    int m = tid + it*256;
    int kb = m >> 4, c = m & 15;
    int k0 = kb*8;
    int gi = c >> 2;
    int d  = dg16 + sub4 + (c & 3);
    size_t gr = (size_t)(gi*1024 + d)*1024;
    const u16* s1 = (k0 < 1024) ? (w1c + gr + k0) : (wh1 + gr + k0 - 1024);
    const u16* s0 = (k0 < 1024) ? (w0c + gr + k0) : (wh0 + gr + k0 - 1024);
    *(u16x8*)(lw1 + (m << 3)) = *(const u16x8*)s1;
    *(u16x8*)(lw0 + (m << 3)) = *(const u16x8*)s0;
  }
  __syncthreads();

  float c0r = 0.f, c1r = 0.f;
  int epoch = 1;
  const int lwoff = ((wv*64 + q)*16 + r) << 3;

  for (int t = 0; t <= NOL; ++t){
    const u16* z0t = z0r + (size_t)t*16384;
    u16* dq_t   = dqr   + (size_t)t*16384;
    float* esc_t= escr  + (size_t)t*8192;
    u16* attc_t = attcr + (size_t)t*16384;

    // ======== Phase A: gemm1+cell1(t-1), dq(t) ========
    if (t >= 1){
      const int s = t - 1;
      const u16* z1p = z1r + (size_t)(t-1)*16384;
      const u16* ab = ((wv < 2) ? z0t : z1p) + r*1024 + (wv & 1)*512 + q*8;
      f32x4 acc = tile_gemm(lw1 + lwoff, ab);
      #pragma unroll
      for (int rr = 0; rr < 4; ++rr) gex[wv][q*4+rr][r] = acc[rr];
      __syncthreads();
      if (tid < 64){
        int b = tid >> 2, dd = tid & 3, d = dg16 + sub4 + dd;
        float g0 = gex[0][b][0*4+dd] + gex[1][b][0*4+dd] + gex[2][b][0*4+dd] + gex[3][b][0*4+dd];
        float g1 = gex[0][b][1*4+dd] + gex[1][b][1*4+dd] + gex[2][b][1*4+dd] + gex[3][b][1*4+dd];
        float g2 = gex[0][b][2*4+dd] + gex[1][b][2*4+dd] + gex[2][b][2*4+dd] + gex[3][b][2*4+dd];
        float g3 = gex[0][b][3*4+dd] + gex[1][b][3*4+dd] + gex[2][b][3*4+dd] + gex[3][b][3*4+dd];
        g0 += bias1[d]; g1 += bias1[1024+d]; g2 += bias1[2048+d]; g3 += bias1[3072+d];
        float cn = sigf(g1)*c1r + sigf(g0)*tanhf(g2);
        float zn = sigf(g3)*tanhf(cn);
        c1r = cn;
        float zn2 = __shfl_down(zn, 1);
        if ((tid & 1) == 0){
          u32 pk = (u32)f2b(zn) | ((u32)f2b(zn2) << 16);
          *(u32*)(zallb + ((size_t)b*NOL + s)*1024 + d) = pk;
          coh_stu((u32*)(z1r + (size_t)t*16384 + b*1024 + d), pk);
        }
      }
      __syncthreads();
    }
    if (t < NOL){
      const int b = tid & 15, ks = tid >> 4;
      float a4[4] = {0.f,0.f,0.f,0.f};
      #pragma unroll
      for (int i = 0; i < 8; ++i){
        bf16x8 za = *(const bf16x8*)(z0t + b*1024 + ks*64 + i*8);
        #pragma unroll
        for (int nn = 0; nn < 4; ++nn){
          bf16x8 wb = *(const bf16x8*)(wdecT + (size_t)(wg*4+nn)*1024 + ks*64 + i*8);
          a4[nn] += dot8(za, wb);
        }
      }
      #pragma unroll
      for (int nn = 0; nn < 4; ++nn) sdq[(ks*16 + b)*4 + nn] = a4[nn];
      __syncthreads();
      if (tid < 64){
        int b2 = tid >> 2, nn = tid & 3;
        float s2 = 0.f;
        #pragma unroll
        for (int ks2 = 0; ks2 < 16; ++ks2) s2 += sdq[(ks2*16 + b2)*4 + nn];
        float dv = tanhf(s2);
        float dv2 = __shfl_down(dv, 1);
        if ((tid & 1) == 0){
          u32 pk = (u32)f2b(dv) | ((u32)f2b(dv2) << 16);
          coh_stu((u32*)(dq_t + b2*1024 + wg*4 + nn), pk);
        }
      }
    }
    gbar(af, epoch++);
    if (t == NOL) break;

    // ======== Phase B: escore = 2 * pre . dq  (32 rows per WG) ========
    {
      const int rbase = wg*32 + wv*8;
      const int b = (wg*32) >> 9;
      const u16* dqb = dq_t + b*1024 + lane*16;
      u16x8 d0 = *(const u16x8*)(dqb);
      u16x8 d1 = *(const u16x8*)(dqb + 8);
      float qv[16];
      #pragma unroll
      for (int j = 0; j < 8; ++j){ qv[j] = b2f(d0[j]); qv[8+j] = b2f(d1[j]); }
      #pragma unroll
      for (int rr = 0; rr < 8; ++rr){
        const u16* pr = pre + (size_t)(rbase+rr)*1024 + lane*16;
        u16x8 p0 = *(const u16x8*)(pr);
        u16x8 p1 = *(const u16x8*)(pr+8);
        float acc = 0.f;
        #pragma unroll
        for (int j = 0; j < 8; ++j){
          acc += b2f(p0[j])*qv[j];
          acc += b2f(p1[j])*qv[8+j];
        }
        #pragma unroll
        for (int off = 32; off > 0; off >>= 1) acc += __shfl_xor(acc, off, 64);
        if (lane == 0) coh_stf(&esc_t[rbase+rr], 2.0f*acc);
      }
    }
    // B -> C dependency is within the 16-WG b-group: cheap one-hop group barrier
    group_bar(gfl, epoch++);

    // ======== Phase C: softmax + att_c (b = wg>>4, 64-col e-slice) ========
    {
      const int b = wg >> 4, ec = wg & 15;
      const int len = hlen[b];
      float e0 = (tid < len)     ? esc_t[b*512 + tid]       : -INFINITY;
      float e1 = (tid+256 < len) ? esc_t[b*512 + tid + 256] : -INFINITY;
      sred[tid] = fmaxf(e0, e1);
      __syncthreads();
      #pragma unroll
      for (int s2 = 128; s2 > 0; s2 >>= 1){
        if (tid < s2) sred[tid] = fmaxf(sred[tid], sred[tid+s2]);
        __syncthreads();
      }
      float mx = sred[0];
      __syncthreads();
      float p0 = (tid < len)     ? expf(e0 - mx) : 0.0f;
      float p1 = (tid+256 < len) ? expf(e1 - mx) : 0.0f;
      sred[tid] = p0 + p1;
      __syncthreads();
      #pragma unroll
      for (int s2 = 128; s2 > 0; s2 >>= 1){
        if (tid < s2) sred[tid] += sred[tid+s2];
        __syncthreads();
      }
      float inv = 1.0f/sred[0];
      sw[tid] = p0*inv; sw[tid+256] = p1*inv;
      __syncthreads();
      const int el = tid & 63, th = tid >> 6;
      const u16* hp = hpadT + ((size_t)b*1024 + ec*64 + el)*512 + th*128;
      float acc = 0.f;
      #pragma unroll
      for (int i = 0; i < 16; ++i){
        u16x8 v = *(const u16x8*)(hp + i*8);
        #pragma unroll
        for (int j = 0; j < 8; ++j) acc += sw[th*128 + i*8 + j]*b2f(v[j]);
      }
      spart[th][el] = acc;
      __syncthreads();
      if (tid < 64){
        float s2 = spart[0][tid]+spart[1][tid]+spart[2][tid]+spart[3][tid];
        float s2n = __shfl_down(s2, 1);
        if ((tid & 1) == 0){
          u32 pk = (u32)f2b(s2) | ((u32)f2b(s2n) << 16);
          coh_stu((u32*)(attc_t + b*1024 + ec*64 + tid), pk);
        }
      }
    }
    gbar(af, epoch++);

    // ======== Phase D: gemm0 + cell0(t) -> z0 ring slot t+1 ========
    {
      const u16* ab = ((wv < 2) ? attc_t : z0t) + r*1024 + (wv & 1)*512 + q*8;
      f32x4 acc = tile_gemm(lw0 + lwoff, ab);
      #pragma unroll
      for (int rr = 0; rr < 4; ++rr) gex[wv][q*4+rr][r] = acc[rr];
      __syncthreads();
      if (tid < 64){
        int b = tid >> 2, dd = tid & 3, d = dg16 + sub4 + dd;
        const u16* gr = gey + ((size_t)b*NOL + t)*4096 + d;
        float g0 = gex[0][b][0*4+dd] + gex[1][b][0*4+dd] + gex[2][b][0*4+dd] + gex[3][b][0*4+dd];
        float g1 = gex[0][b][1*4+dd] + gex[1][b][1*4+dd] + gex[2][b][1*4+dd] + gex[3][b][1*4+dd];
        float g2 = gex[0][b][2*4+dd] + gex[1][b][2*4+dd] + gex[2][b][2*4+dd] + gex[3][b][2*4+dd];
        float g3 = gex[0][b][3*4+dd] + gex[1][b][3*4+dd] + gex[2][b][3*4+dd] + gex[3][b][3*4+dd];
        g0 += b2f(gr[0]); g1 += b2f(gr[1024]); g2 += b2f(gr[2048]); g3 += b2f(gr[3072]);
        float cn = sigf(g1)*c0r + sigf(g0)*tanhf(g2);
        float zn = sigf(g3)*tanhf(cn);
        c0r = cn;
        float zn2 = __shfl_down(zn, 1);
        if ((tid & 1) == 0){
          u32 pk = (u32)f2b(zn) | ((u32)f2b(zn2) << 16);
          coh_stu((u32*)(z0r + (size_t)(t+1)*16384 + b*1024 + d), pk);
        }
      }
    }
    gbar(af, epoch++);
  }
}

// ---------------- per-row single-pass online log_softmax + NLL + argmax ----------------
__global__ __launch_bounds__(256) void loss_kernel(
    const u16* __restrict__ logits, const int* __restrict__ ys, float* __restrict__ accum){
  int row = blockIdx.x;
  int tid = threadIdx.x;
  const u16* lr = logits + (size_t)row * NO;
  __shared__ float sm[256], ss[256];
  __shared__ int   si[256];
  float m = -INFINITY, s = 0.f; int mi = 0x7FFFFFFF;
  for (int n = tid; n < NO; n += 256){
    float v = b2f(lr[n]);
    if (v > m){
      s = s*__expf(m - v) + 1.0f;
      m = v; mi = n;
    } else {
      s += __expf(v - m);
    }
  }
  sm[tid] = m; ss[tid] = s; si[tid] = mi;
  __syncthreads();
  for (int st = 128; st > 0; st >>= 1){
    if (tid < st){
      float m1 = sm[tid], s1 = ss[tid]; int i1 = si[tid];
      float m2 = sm[tid+st], s2 = ss[tid+st]; int i2 = si[tid+st];
      float M = fmaxf(m1, m2);
      ss[tid] = s1*__expf(m1 - M) + s2*__expf(m2 - M);
      sm[tid] = M;
      si[tid] = (m1 > m2) ? i1 : (m2 > m1) ? i2 : min(i1, i2);
    }
    __syncthreads();
  }
  if (tid == 0){
    int b = row / NOL, l = row - b*NOL;
    int label = (l < NL) ? ys[b*NL + l] : TOK_EOS;
    float lse = sm[0] + logf(ss[0]);
    float nll = lse - b2f(lr[label]);
    atomicAdd(&accum[0], nll);
    atomicAdd(&accum[1], (si[0]==label) ? 1.0f : 0.0f);
  }
}

__global__ void finalize_kernel(const float* __restrict__ accum, float* __restrict__ out){
  out[0] = accum[0] / (float)NROWS * (float)(NOL-1);
  out[1] = accum[1] / (float)NROWS;
}

extern "C" void kernel_launch(void* const* d_in, const int* in_sizes, int n_in,
                              void* d_out, int out_size, void* d_ws, size_t ws_size,
                              hipStream_t stream){
  const float* hpad  = (const float*)d_in[0];
  const int*   hlen  = (const int*)  d_in[1];
  const int*   ys    = (const int*)  d_in[2];
  const float* embed = (const float*)d_in[3];
  const float* Wenc  = (const float*)d_in[4];
  const float* Wdec  = (const float*)d_in[5];
  const float* Wih0  = (const float*)d_in[6];
  const float* Whh0  = (const float*)d_in[7];
  const float* bih0  = (const float*)d_in[8];
  const float* bhh0  = (const float*)d_in[9];
  const float* Wih1  = (const float*)d_in[10];
  const float* Whh1  = (const float*)d_in[11];
  const float* bih1  = (const float*)d_in[12];
  const float* bhh1  = (const float*)d_in[13];
  const float* Wout  = (const float*)d_in[14];
  const float* bout  = (const float*)d_in[15];
  float* out = (float*)d_out;

  char* ws = (char*)d_ws;
  size_t cur = 0;
  auto alloc = [&](size_t bytes) -> char* {
    char* p = ws + cur;
    cur += (bytes + 255) & ~(size_t)255;
    return p;
  };
  u16*   pre_bf   = (u16*)  alloc(16777216);   // [8192][1024]
  u16*   hpadT    = (u16*)  alloc(16777216);   // [16][1024][512]
  u16*   w0c      = (u16*)  alloc(8388608);    // Wih0[:,1024:]
  u16*   wh0      = (u16*)  alloc(8388608);
  u16*   w1c      = (u16*)  alloc(8388608);
  u16*   wh1      = (u16*)  alloc(8388608);
  u16*   wdecT    = (u16*)  alloc(2097152);    // [1024][1024]
  u16*   wencT    = (u16*)  alloc(2097152);    // [1024][1024]
  u16*   woutT    = (u16*)  alloc(20709376);   // [10112][1024]
  u16*   gey      = (u16*)  alloc(16908288);   // [2064][4096]
  u16*   zallb    = (u16*)  alloc(4456448);    // [2176][1024]
  u16*   logits   = (u16*)  alloc(41280000);   // [2064][10000]
  float* bias1    = (float*)alloc(16384);
  // ---- write-once rings ----
  u16*   dqr      = (u16*)  alloc(129u*32768); // [129][16][1024] bf16
  float* escr     = (float*)alloc(129u*32768); // [129][16][512] f32
  u16*   attcr    = (u16*)  alloc(129u*32768); // [129][16][1024] bf16
  u16*   z0r      = (u16*)  alloc(130u*32768); // [130][16][1024] bf16
  u16*   z1r      = (u16*)  alloc(130u*32768); // [130][16][1024] bf16
  // ---- zeroed each launch ----
  u32*   af       = (u32*)  alloc(32768);      // grid barrier flags
  u32*   gfl      = (u32*)  alloc(32768);      // group barrier flags
  float* accum    = (float*)alloc(128);

  // pre-seq staging buffers ALIAS the logits region (dead until logits_g)
  u16*   hpad_bf  = (u16*)logits;              // 16777216 B
  u16*   eys      = (u16*)(logits + 8388608);  // 4456448 B (u16 offset 8388608 = 16 MB)
  u16*   w0e      = (u16*)(logits + 11165696); // 8388608 B

  // zero: af+gfl+accum (32768+32768+128 = 65664 -> 4104 uint4), z0r slot0, z1r slot0
  zero4_kernel<<<17, 256, 0, stream>>>((uint4*)af, 4104);
  zero4_kernel<<<8, 256, 0, stream>>>((uint4*)z0r, 2048);
  zero4_kernel<<<8, 256, 0, stream>>>((uint4*)z1r, 2048);

  tcvt_kernel<<<dim3(32,32),  256, 0, stream>>>(Wenc, 1024, 1024, wencT);
  tcvt_kernel<<<dim3(32,32),  256, 0, stream>>>(Wdec, 1024, 1024, wdecT);
  tcvt_kernel<<<dim3(316,32), 256, 0, stream>>>(Wout, 1024, NO,   woutT);
  cvt_nk_kernel<<<4096, 256, 0, stream>>>(Wih0, 2048, 1024, w0c);
  cvt_nk_kernel<<<4096, 256, 0, stream>>>(Whh0, 1024, 0, wh0);
  cvt_nk_kernel<<<4096, 256, 0, stream>>>(Wih1, 1024, 0, w1c);
  cvt_nk_kernel<<<4096, 256, 0, stream>>>(Whh1, 1024, 0, wh1);
  cvt_nk_kernel<<<4096, 256, 0, stream>>>(Wih0, 2048, 0, w0e);
  hpadbf_kernel<<<8192, 256, 0, stream>>>(hpad, hlen, hpad_bf);
  hpadT_kernel<<<dim3(32,16,16), 256, 0, stream>>>(hpad, hlen, hpadT);
  bias_add_kernel<<<16, 256, 0, stream>>>(bih1, bhh1, bias1);
  eys_kernel<<<2176, 256, 0, stream>>>(ys, embed, eys);

  preenc_g<<<dim3(64, 8),  256, 0, stream>>>(hpad_bf, wencT, pre_bf);
  gey_g   <<<dim3(17, 32), 256, 0, stream>>>(eys, w0e, bih0, bhh0, gey);

  hipFuncSetAttribute((const void*)seq_kernel,
                      hipFuncAttributeMaxDynamicSharedMemorySize, 131072);
  seq_kernel<<<NBLK, 256, 131072, stream>>>(pre_bf, hpadT, w0c, wh0, w1c, wh1,
                                            wdecT, gey, bias1, hlen,
                                            dqr, escr, attcr, z0r, z1r, zallb, af, gfl);

  logits_g<<<dim3(17, 79), 256, 0, stream>>>(zallb, woutT, bout, logits);
  loss_kernel<<<NROWS, 256, 0, stream>>>(logits, ys, accum);
  finalize_kernel<<<1, 1, 0, stream>>>(accum, out);
}